// Round 3
// baseline (3870.603 us; speedup 1.0000x reference)
//
#include <hip/hip_runtime.h>

// ChebNet: 3x ChebConv(K=5) + relu + linear head. N=100000, E=1600000, HID=64.
// R3: bf16 gather operand (halves random-row fetch), matmul fused into gather
// (Tx row via per-wave LDS slot, W column in registers), fp32 recurrence.

#define TB 256

typedef unsigned short u16;

__device__ inline u16 f2bf(float v) {            // RNE fp32 -> bf16
    unsigned u = __float_as_uint(v);
    return (u16)((u + 0x7fffu + ((u >> 16) & 1u)) >> 16);
}
__device__ inline float bf2f(u16 v) {
    return __uint_as_float(((unsigned)v) << 16);
}

// ---------- degree / histogram (fused) ----------
__global__ __launch_bounds__(TB) void k_counts(const int* __restrict__ src,
                                               const int* __restrict__ dst,
                                               int* __restrict__ cs,
                                               int* __restrict__ cd, int E) {
    int e = blockIdx.x * TB + threadIdx.x;
    if (e < E) {
        atomicAdd(&cs[src[e]], 1);
        atomicAdd(&cd[dst[e]], 1);
    }
}

__global__ __launch_bounds__(TB) void k_dinv(const int* __restrict__ cs,
                                             float* __restrict__ dinv, int N) {
    int n = blockIdx.x * TB + threadIdx.x;
    if (n < N) {
        int d = cs[n];
        dinv[n] = d > 0 ? rsqrtf((float)d) : 0.f;
    }
}

// ---------- CSR build ----------
__global__ __launch_bounds__(TB) void k_scan_a(const int* __restrict__ cnt,
                                               int* __restrict__ excl,
                                               int* __restrict__ bsum, int N) {
    __shared__ int s[TB];
    int t = threadIdx.x;
    int i = blockIdx.x * TB + t;
    int v = (i < N) ? cnt[i] : 0;
    s[t] = v;
    __syncthreads();
    for (int o = 1; o < TB; o <<= 1) {
        int add = (t >= o) ? s[t - o] : 0;
        __syncthreads();
        s[t] += add;
        __syncthreads();
    }
    if (i < N) excl[i] = s[t] - v;
    if (t == TB - 1) bsum[blockIdx.x] = s[t];
}

__global__ __launch_bounds__(1024) void k_scan_b(int* __restrict__ bsum, int nb) {
    __shared__ int s[1024];
    int t = threadIdx.x;
    int v = (t < nb) ? bsum[t] : 0;
    s[t] = v;
    __syncthreads();
    for (int o = 1; o < 1024; o <<= 1) {
        int add = (t >= o) ? s[t - o] : 0;
        __syncthreads();
        s[t] += add;
        __syncthreads();
    }
    if (t < nb) bsum[t] = s[t] - v;
}

__global__ __launch_bounds__(TB) void k_scan_c(int* __restrict__ rowptr,
                                               int* __restrict__ wr,
                                               const int* __restrict__ bsum,
                                               int N, int E) {
    int i = blockIdx.x * TB + threadIdx.x;
    if (i < N) {
        int r = rowptr[i] + bsum[blockIdx.x];
        rowptr[i] = r;
        wr[i] = r;
    }
    if (i == 0) rowptr[N] = E;
}

__global__ __launch_bounds__(TB) void k_fill(const int* __restrict__ src,
                                             const int* __restrict__ dst,
                                             const float* __restrict__ dinv,
                                             int* __restrict__ wr,
                                             int2* __restrict__ csr, int E) {
    int e = blockIdx.x * TB + threadIdx.x;
    if (e < E) {
        int s = src[e], d = dst[e];
        float w = -dinv[s] * dinv[d];
        int pos = atomicAdd(&wr[d], 1);
        csr[pos] = make_int2(s, __float_as_int(w));
    }
}

// ---------- layer-1 (Fin=1) props: 16 lanes per node ----------
__global__ __launch_bounds__(TB) void k_gather1(const float* __restrict__ in,
                                                const float* __restrict__ prev,
                                                float* __restrict__ out,
                                                const int* __restrict__ rowptr,
                                                const int2* __restrict__ csr,
                                                float scale, float scale0, int N) {
    int l16 = threadIdx.x & 15;
    int n = blockIdx.x * (TB / 16) + (threadIdx.x >> 4);
    if (n >= N) return;
    int beg = rowptr[n], end = rowptr[n + 1];
    float s = 0.f;
    for (int i = beg + l16; i < end; i += 16) {
        int2 e = csr[i];
        s = fmaf(__int_as_float(e.y), in[e.x], s);
    }
    s += __shfl_down(s, 8, 16);
    s += __shfl_down(s, 4, 16);
    s += __shfl_down(s, 2, 16);
    s += __shfl_down(s, 1, 16);
    if (l16 == 0) out[n] = fmaf(scale, s, scale0 * prev[n]);
}

// Layer 1 combine: h = relu(b1 + sum_k t_k * W1[k]); writes fp32 + bf16
__global__ __launch_bounds__(TB) void k_layer1(const float* __restrict__ x,
                                               const float* __restrict__ t1,
                                               const float* __restrict__ t2,
                                               const float* __restrict__ t3,
                                               const float* __restrict__ t4,
                                               const float* __restrict__ W1,
                                               const float* __restrict__ b1,
                                               float* __restrict__ Hf,
                                               u16* __restrict__ Hb, int N) {
    int tid = blockIdx.x * TB + threadIdx.x;
    if (tid >= N * 64) return;
    int n = tid >> 6, f = tid & 63;
    float v = b1[f];
    v = fmaf(x[n],  W1[f],       v);
    v = fmaf(t1[n], W1[64 + f],  v);
    v = fmaf(t2[n], W1[128 + f], v);
    v = fmaf(t3[n], W1[192 + f], v);
    v = fmaf(t4[n], W1[256 + f], v);
    v = fmaxf(v, 0.f);
    Hf[tid] = v;
    Hb[tid] = f2bf(v);
}

// ---------- k=0 dense: ACC = bias + Tx0 @ W0 ----------
__global__ __launch_bounds__(TB) void k_matmul0(const float* __restrict__ Tx,
                                                const float* __restrict__ Wk,
                                                const float* __restrict__ bias,
                                                float* __restrict__ acc, int N) {
    int lane = threadIdx.x & 63;
    int wid = blockIdx.x * (TB / 64) + (threadIdx.x >> 6);
    int nw = gridDim.x * (TB / 64);
    float wcol[64];
#pragma unroll
    for (int j = 0; j < 64; ++j) wcol[j] = Wk[j * 64 + lane];
    float bv = bias[lane];
    for (int n = wid; n < N; n += nw) {
        const float4* row = (const float4*)(Tx + (size_t)n * 64);
        float a = bv;
#pragma unroll
        for (int j4 = 0; j4 < 16; ++j4) {
            float4 t = row[j4];
            a = fmaf(t.x, wcol[4 * j4 + 0], a);
            a = fmaf(t.y, wcol[4 * j4 + 1], a);
            a = fmaf(t.z, wcol[4 * j4 + 2], a);
            a = fmaf(t.w, wcol[4 * j4 + 3], a);
        }
        acc[(size_t)n * 64 + lane] = a;
    }
}

// ---------- fused prop (bf16 gather) + recurrence (fp32) + matmul ----------
// T[n][f] = scale * sum_e w_e * bf2f(inb[src_e][f]) + scale0 * prev[n][f]
// acc[n][f] += sum_j T[n][j] * Wk[j][f]        (T row via per-wave LDS slot)
// finalRelu=0: write T -> outF (fp32) + outB (bf16), update acc
// finalRelu=1: h = relu(acc + contrib) -> outF + outB; acc not written; T not stored
__global__ __launch_bounds__(TB) void k_gmm(const u16* __restrict__ inb,
                                            const float* __restrict__ prev,
                                            float* __restrict__ outF,
                                            u16* __restrict__ outB,
                                            float* __restrict__ acc,
                                            const float* __restrict__ Wk,
                                            const int* __restrict__ rowptr,
                                            const int2* __restrict__ csr,
                                            float scale, float scale0,
                                            int finalRelu, int N) {
    __shared__ float lds[TB / 64][64];
    int lane = threadIdx.x & 63;
    int ws = threadIdx.x >> 6;
    int wid = blockIdx.x * (TB / 64) + ws;
    int nw = gridDim.x * (TB / 64);

    float wcol[64];
#pragma unroll
    for (int j = 0; j < 64; ++j) wcol[j] = Wk[j * 64 + lane];

    for (int n = wid; n < N; n += nw) {
        int beg = rowptr[n], end = rowptr[n + 1];
        float s = 0.f;
        for (int i = beg; i < end; ++i) {
            int2 e = csr[i];
            s = fmaf(__int_as_float(e.y), bf2f(inb[(size_t)e.x * 64 + lane]), s);
        }
        float T = scale * s;
        if (scale0 != 0.f) T = fmaf(scale0, prev[(size_t)n * 64 + lane], T);

        lds[ws][lane] = T;
        __builtin_amdgcn_wave_barrier();   // same-wave DS ordering; no block sync needed

        float a = acc[(size_t)n * 64 + lane];
        const float4* row = (const float4*)lds[ws];
#pragma unroll
        for (int j4 = 0; j4 < 16; ++j4) {
            float4 t = row[j4];
            a = fmaf(t.x, wcol[4 * j4 + 0], a);
            a = fmaf(t.y, wcol[4 * j4 + 1], a);
            a = fmaf(t.z, wcol[4 * j4 + 2], a);
            a = fmaf(t.w, wcol[4 * j4 + 3], a);
        }
        __builtin_amdgcn_wave_barrier();

        size_t o = (size_t)n * 64 + lane;
        if (finalRelu) {
            float h = fmaxf(a, 0.f);
            outF[o] = h;
            outB[o] = f2bf(h);
        } else {
            acc[o] = a;
            outF[o] = T;
            outB[o] = f2bf(T);
        }
    }
}

__global__ __launch_bounds__(TB) void k_final(const float* __restrict__ A,
                                              const float* __restrict__ Wfc,
                                              const float* __restrict__ bfc,
                                              float* __restrict__ out, int N) {
    int lane = threadIdx.x & 63;
    int wid = blockIdx.x * (TB / 64) + (threadIdx.x >> 6);
    if (wid >= N) return;
    float v = A[(size_t)wid * 64 + lane] * Wfc[lane];
#pragma unroll
    for (int o = 32; o > 0; o >>= 1) v += __shfl_down(v, o, 64);
    if (lane == 0) out[wid] = v + bfc[0];
}

extern "C" void kernel_launch(void* const* d_in, const int* in_sizes, int n_in,
                              void* d_out, int out_size, void* d_ws, size_t ws_size,
                              hipStream_t stream) {
    const float* x   = (const float*)d_in[0];
    const int*   ei  = (const int*)d_in[1];
    const float* W1  = (const float*)d_in[2];
    const float* b1  = (const float*)d_in[3];
    const float* W2  = (const float*)d_in[4];
    const float* b2  = (const float*)d_in[5];
    const float* W3  = (const float*)d_in[6];
    const float* b3  = (const float*)d_in[7];
    const float* Wfc = (const float*)d_in[8];
    const float* bfc = (const float*)d_in[9];
    float* out = (float*)d_out;

    const int N = in_sizes[0];
    const int E = in_sizes[1] / 2;
    const int* src = ei;
    const int* dst = ei + E;
    const size_t NF = (size_t)N * 64;

    // workspace layout
    char* p = (char*)d_ws;
    float* Pa  = (float*)p; p += NF * 4;      // fp32 Tx rotation
    float* Pb  = (float*)p; p += NF * 4;
    float* Pc  = (float*)p; p += NF * 4;
    float* ACC = (float*)p; p += NF * 4;
    u16* Qa = (u16*)p; p += NF * 2;           // bf16 Tx rotation
    u16* Qb = (u16*)p; p += NF * 2;
    int2* csr = (int2*)p; p += (size_t)E * 8;
    float* t1 = (float*)p; p += (size_t)N * 4;
    float* t2 = (float*)p; p += (size_t)N * 4;
    float* t3 = (float*)p; p += (size_t)N * 4;
    float* t4 = (float*)p; p += (size_t)N * 4;
    float* dinv = (float*)p; p += (size_t)N * 4;
    int* cs     = (int*)p; p += (size_t)N * 4;
    int* cd     = (int*)p; p += (size_t)N * 4;
    int* rowptr = (int*)p; p += (size_t)(N + 1) * 4;
    int* wr     = (int*)p; p += (size_t)N * 4;
    int* bsum   = (int*)p; p += 1024 * 4;

    const int gE  = (E + TB - 1) / TB;
    const int gN  = (N + TB - 1) / TB;                 // scan blocks (<=1024)
    const int gN16 = (N * 16 + TB - 1) / TB;           // 16 lanes/node
    const int gNW = (N + 3) / 4;                       // wave-per-node
    const int gNF = (int)((NF + TB - 1) / TB);
    const int gMM = 512;

    // norm + CSR build
    hipMemsetAsync(cs, 0, (size_t)N * 4, stream);
    hipMemsetAsync(cd, 0, (size_t)N * 4, stream);
    k_counts<<<gE, TB, 0, stream>>>(src, dst, cs, cd, E);
    k_dinv<<<gN, TB, 0, stream>>>(cs, dinv, N);
    k_scan_a<<<gN, TB, 0, stream>>>(cd, rowptr, bsum, N);
    k_scan_b<<<1, 1024, 0, stream>>>(bsum, gN);
    k_scan_c<<<gN, TB, 0, stream>>>(rowptr, wr, bsum, N, E);
    k_fill<<<gE, TB, 0, stream>>>(src, dst, dinv, wr, csr, E);

    // --- Layer 1 (Fin=1) ---
    k_gather1<<<gN16, TB, 0, stream>>>(x,  x,  t1, rowptr, csr, 1.f,  0.f, N);
    k_gather1<<<gN16, TB, 0, stream>>>(t1, x,  t2, rowptr, csr, 2.f, -1.f, N);
    k_gather1<<<gN16, TB, 0, stream>>>(t2, t1, t3, rowptr, csr, 2.f, -1.f, N);
    k_gather1<<<gN16, TB, 0, stream>>>(t3, t2, t4, rowptr, csr, 2.f, -1.f, N);
    k_layer1<<<gNF, TB, 0, stream>>>(x, t1, t2, t3, t4, W1, b1, Pa, Qa, N);

    // --- Layers 2 & 3 (Fin=64) ---
    // Input h = (Pa, Qa). Rotation per layer:
    //   mm0:  ACC = b + Pa@W0
    //   T1 -> (Pb, Qb)  in=Qa  prev=--     s=1, s0=0
    //   T2 -> (Pc, Qa)  in=Qb  prev=Pa    s=2, s0=-1
    //   T3 -> (Pa, Qb)  in=Qa  prev=Pb    s=2, s0=-1
    //   h' -> (Pb, Qa)  in=Qb  prev=Pc    s=2, s0=-1, relu (T4 not stored)
    for (int layer = 0; layer < 2; ++layer) {
        const float* W = (layer == 0) ? W2 : W3;
        const float* b = (layer == 0) ? b2 : b3;
        k_matmul0<<<gMM, TB, 0, stream>>>(Pa, W + 0 * 4096, b, ACC, N);
        k_gmm<<<gMM, TB, 0, stream>>>(Qa, Pa, Pb, Qb, ACC, W + 1 * 4096,
                                      rowptr, csr, 1.f,  0.f, 0, N);
        k_gmm<<<gMM, TB, 0, stream>>>(Qb, Pa, Pc, Qa, ACC, W + 2 * 4096,
                                      rowptr, csr, 2.f, -1.f, 0, N);
        k_gmm<<<gMM, TB, 0, stream>>>(Qa, Pb, Pa, Qb, ACC, W + 3 * 4096,
                                      rowptr, csr, 2.f, -1.f, 0, N);
        k_gmm<<<gMM, TB, 0, stream>>>(Qb, Pc, Pb, Qa, ACC, W + 4 * 4096,
                                      rowptr, csr, 2.f, -1.f, 1, N);
        // next layer input = (Pb, Qa); rotate fp32 buffers
        float* tmp = Pa; Pa = Pb; Pb = Pc; Pc = tmp;
    }

    // --- Final head: h = (Pa, Qa) after rotation ---
    k_final<<<gNW, TB, 0, stream>>>(Pa, Wfc, bfc, out, N);
}

// Round 4
// 1698.380 us; speedup vs baseline: 2.2790x; 2.2790x over previous
//
#include <hip/hip_runtime.h>

// ChebNet: 3x ChebConv(K=5) + relu + linear head. N=100000, E=1600000, HID=64.
// R4: separate gather/matmul (R2 shape), bf16 gather rows with TWO EDGES PER
// WAVE (u32/lane, halves combined via shfl_xor 32), fp32 recurrence + matmul,
// full grids (gather: wave/node; matmul: 3200 blocks grid-stride).

#define TB 256

typedef unsigned short u16;
typedef unsigned int u32;

__device__ inline u16 f2bf(float v) {            // RNE fp32 -> bf16
    unsigned u = __float_as_uint(v);
    return (u16)((u + 0x7fffu + ((u >> 16) & 1u)) >> 16);
}

// ---------- degree / histogram (fused) ----------
__global__ __launch_bounds__(TB) void k_counts(const int* __restrict__ src,
                                               const int* __restrict__ dst,
                                               int* __restrict__ cs,
                                               int* __restrict__ cd, int E) {
    int e = blockIdx.x * TB + threadIdx.x;
    if (e < E) {
        atomicAdd(&cs[src[e]], 1);
        atomicAdd(&cd[dst[e]], 1);
    }
}

__global__ __launch_bounds__(TB) void k_dinv(const int* __restrict__ cs,
                                             float* __restrict__ dinv, int N) {
    int n = blockIdx.x * TB + threadIdx.x;
    if (n < N) {
        int d = cs[n];
        dinv[n] = d > 0 ? rsqrtf((float)d) : 0.f;
    }
}

// ---------- CSR build ----------
__global__ __launch_bounds__(TB) void k_scan_a(const int* __restrict__ cnt,
                                               int* __restrict__ excl,
                                               int* __restrict__ bsum, int N) {
    __shared__ int s[TB];
    int t = threadIdx.x;
    int i = blockIdx.x * TB + t;
    int v = (i < N) ? cnt[i] : 0;
    s[t] = v;
    __syncthreads();
    for (int o = 1; o < TB; o <<= 1) {
        int add = (t >= o) ? s[t - o] : 0;
        __syncthreads();
        s[t] += add;
        __syncthreads();
    }
    if (i < N) excl[i] = s[t] - v;
    if (t == TB - 1) bsum[blockIdx.x] = s[t];
}

__global__ __launch_bounds__(1024) void k_scan_b(int* __restrict__ bsum, int nb) {
    __shared__ int s[1024];
    int t = threadIdx.x;
    int v = (t < nb) ? bsum[t] : 0;
    s[t] = v;
    __syncthreads();
    for (int o = 1; o < 1024; o <<= 1) {
        int add = (t >= o) ? s[t - o] : 0;
        __syncthreads();
        s[t] += add;
        __syncthreads();
    }
    if (t < nb) bsum[t] = s[t] - v;
}

__global__ __launch_bounds__(TB) void k_scan_c(int* __restrict__ rowptr,
                                               int* __restrict__ wr,
                                               const int* __restrict__ bsum,
                                               int N, int E) {
    int i = blockIdx.x * TB + threadIdx.x;
    if (i < N) {
        int r = rowptr[i] + bsum[blockIdx.x];
        rowptr[i] = r;
        wr[i] = r;
    }
    if (i == 0) rowptr[N] = E;
}

__global__ __launch_bounds__(TB) void k_fill(const int* __restrict__ src,
                                             const int* __restrict__ dst,
                                             const float* __restrict__ dinv,
                                             int* __restrict__ wr,
                                             int2* __restrict__ csr, int E) {
    int e = blockIdx.x * TB + threadIdx.x;
    if (e < E) {
        int s = src[e], d = dst[e];
        float w = -dinv[s] * dinv[d];
        int pos = atomicAdd(&wr[d], 1);
        csr[pos] = make_int2(s, __float_as_int(w));
    }
}

// ---------- layer-1 (Fin=1) props: 16 lanes per node ----------
__global__ __launch_bounds__(TB) void k_gather1(const float* __restrict__ in,
                                                const float* __restrict__ prev,
                                                float* __restrict__ out,
                                                const int* __restrict__ rowptr,
                                                const int2* __restrict__ csr,
                                                float scale, float scale0, int N) {
    int l16 = threadIdx.x & 15;
    int n = blockIdx.x * (TB / 16) + (threadIdx.x >> 4);
    if (n >= N) return;
    int beg = rowptr[n], end = rowptr[n + 1];
    float s = 0.f;
    for (int i = beg + l16; i < end; i += 16) {
        int2 e = csr[i];
        s = fmaf(__int_as_float(e.y), in[e.x], s);
    }
    s += __shfl_down(s, 8, 16);
    s += __shfl_down(s, 4, 16);
    s += __shfl_down(s, 2, 16);
    s += __shfl_down(s, 1, 16);
    if (l16 == 0) out[n] = fmaf(scale, s, scale0 * prev[n]);
}

// Layer 1 combine: h = relu(b1 + sum_k t_k * W1[k]); writes fp32 + bf16
__global__ __launch_bounds__(TB) void k_layer1(const float* __restrict__ x,
                                               const float* __restrict__ t1,
                                               const float* __restrict__ t2,
                                               const float* __restrict__ t3,
                                               const float* __restrict__ t4,
                                               const float* __restrict__ W1,
                                               const float* __restrict__ b1,
                                               float* __restrict__ Hf,
                                               u16* __restrict__ Hb, int N) {
    int tid = blockIdx.x * TB + threadIdx.x;
    if (tid >= N * 64) return;
    int n = tid >> 6, f = tid & 63;
    float v = b1[f];
    v = fmaf(x[n],  W1[f],       v);
    v = fmaf(t1[n], W1[64 + f],  v);
    v = fmaf(t2[n], W1[128 + f], v);
    v = fmaf(t3[n], W1[192 + f], v);
    v = fmaf(t4[n], W1[256 + f], v);
    v = fmaxf(v, 0.f);
    Hf[tid] = v;
    Hb[tid] = f2bf(v);
}

// ---------- prop: bf16 gather, TWO edges per wave ----------
// half-wave h processes edges beg+h, beg+h+2, ...; lane p (0..31) of each half
// covers features (2p, 2p+1) via one u32 load. Halves combined by shfl_xor 32.
// outF[n][:] = scale*sum + scale0*prev[n][:]; outB = bf16 of outF.
__global__ __launch_bounds__(TB) void k_gather64p(const u16* __restrict__ inb,
                                                  const float* __restrict__ prev,
                                                  float* __restrict__ outF,
                                                  u16* __restrict__ outB,
                                                  const int* __restrict__ rowptr,
                                                  const int2* __restrict__ csr,
                                                  float scale, float scale0, int N) {
    int lane = threadIdx.x & 63;
    int half = lane >> 5;
    int p = lane & 31;
    int n = blockIdx.x * (TB / 64) + (threadIdx.x >> 6);
    if (n >= N) return;
    int beg = rowptr[n], end = rowptr[n + 1];
    float s0 = 0.f, s1 = 0.f;
    for (int i = beg + half; i < end; i += 2) {
        int2 e = csr[i];
        u32 v = *(const u32*)(inb + (size_t)e.x * 64 + 2 * p);
        float w = __int_as_float(e.y);
        s0 = fmaf(w, __uint_as_float(v << 16), s0);
        s1 = fmaf(w, __uint_as_float(v & 0xffff0000u), s1);
    }
    s0 += __shfl_xor(s0, 32, 64);
    s1 += __shfl_xor(s1, 32, 64);
    if (half == 0) {
        size_t o = (size_t)n * 64 + 2 * p;
        float t0 = scale * s0, t1 = scale * s1;
        if (scale0 != 0.f) {
            float2 pv = *(const float2*)(prev + o);
            t0 = fmaf(scale0, pv.x, t0);
            t1 = fmaf(scale0, pv.y, t1);
        }
        *(float2*)(outF + o) = make_float2(t0, t1);
        *(u32*)(outB + o) = ((u32)f2bf(t1) << 16) | (u32)f2bf(t0);
    }
}

// ---------- dense: acc[n][f] (+)= sum_j Tx[n][j] * Wk[j][f] (+bias on init) ----------
__global__ __launch_bounds__(TB) void k_matmul(const float* __restrict__ Tx,
                                               const float* __restrict__ Wk,
                                               const float* __restrict__ bias,
                                               float* __restrict__ acc,
                                               int initFlag, int N) {
    int lane = threadIdx.x & 63;
    int wid = blockIdx.x * (TB / 64) + (threadIdx.x >> 6);
    int nw = gridDim.x * (TB / 64);

    float wcol[64];
#pragma unroll
    for (int j = 0; j < 64; ++j) wcol[j] = Wk[j * 64 + lane];
    float bv = bias[lane];

    for (int n = wid; n < N; n += nw) {
        const float4* row = (const float4*)(Tx + (size_t)n * 64);
        float a = initFlag ? bv : acc[(size_t)n * 64 + lane];
#pragma unroll
        for (int j4 = 0; j4 < 16; ++j4) {
            float4 t = row[j4];
            a = fmaf(t.x, wcol[4 * j4 + 0], a);
            a = fmaf(t.y, wcol[4 * j4 + 1], a);
            a = fmaf(t.z, wcol[4 * j4 + 2], a);
            a = fmaf(t.w, wcol[4 * j4 + 3], a);
        }
        acc[(size_t)n * 64 + lane] = a;
    }
}

// relu writing fp32 + packed bf16 (4 elems/thread)
__global__ __launch_bounds__(TB) void k_relu2(const float4* __restrict__ in,
                                              float4* __restrict__ outF,
                                              uint2* __restrict__ outB, int n4) {
    int i = blockIdx.x * TB + threadIdx.x;
    if (i >= n4) return;
    float4 v = in[i];
    v.x = fmaxf(v.x, 0.f); v.y = fmaxf(v.y, 0.f);
    v.z = fmaxf(v.z, 0.f); v.w = fmaxf(v.w, 0.f);
    outF[i] = v;
    uint2 b;
    b.x = ((u32)f2bf(v.y) << 16) | (u32)f2bf(v.x);
    b.y = ((u32)f2bf(v.w) << 16) | (u32)f2bf(v.z);
    outB[i] = b;
}

__global__ __launch_bounds__(TB) void k_final(const float* __restrict__ A,
                                              const float* __restrict__ Wfc,
                                              const float* __restrict__ bfc,
                                              float* __restrict__ out, int N) {
    int lane = threadIdx.x & 63;
    int wid = blockIdx.x * (TB / 64) + (threadIdx.x >> 6);
    if (wid >= N) return;
    float v = A[(size_t)wid * 64 + lane] * Wfc[lane];
#pragma unroll
    for (int o = 32; o > 0; o >>= 1) v += __shfl_down(v, o, 64);
    if (lane == 0) out[wid] = v + bfc[0];
}

extern "C" void kernel_launch(void* const* d_in, const int* in_sizes, int n_in,
                              void* d_out, int out_size, void* d_ws, size_t ws_size,
                              hipStream_t stream) {
    const float* x   = (const float*)d_in[0];
    const int*   ei  = (const int*)d_in[1];
    const float* W1  = (const float*)d_in[2];
    const float* b1  = (const float*)d_in[3];
    const float* W2  = (const float*)d_in[4];
    const float* b2  = (const float*)d_in[5];
    const float* W3  = (const float*)d_in[6];
    const float* b3  = (const float*)d_in[7];
    const float* Wfc = (const float*)d_in[8];
    const float* bfc = (const float*)d_in[9];
    float* out = (float*)d_out;

    const int N = in_sizes[0];
    const int E = in_sizes[1] / 2;
    const int* src = ei;
    const int* dst = ei + E;
    const size_t NF = (size_t)N * 64;

    // workspace layout
    char* p = (char*)d_ws;
    float* Pa  = (float*)p; p += NF * 4;      // fp32 Tx rotation
    float* Pb  = (float*)p; p += NF * 4;
    float* Pc  = (float*)p; p += NF * 4;
    float* ACC = (float*)p; p += NF * 4;
    u16* Qa = (u16*)p; p += NF * 2;           // bf16 Tx rotation
    u16* Qb = (u16*)p; p += NF * 2;
    int2* csr = (int2*)p; p += (size_t)E * 8;
    float* t1 = (float*)p; p += (size_t)N * 4;
    float* t2 = (float*)p; p += (size_t)N * 4;
    float* t3 = (float*)p; p += (size_t)N * 4;
    float* t4 = (float*)p; p += (size_t)N * 4;
    float* dinv = (float*)p; p += (size_t)N * 4;
    int* cs     = (int*)p; p += (size_t)N * 4;
    int* cd     = (int*)p; p += (size_t)N * 4;
    int* rowptr = (int*)p; p += (size_t)(N + 1) * 4;
    int* wr     = (int*)p; p += (size_t)N * 4;
    int* bsum   = (int*)p; p += 1024 * 4;

    const int gE   = (E + TB - 1) / TB;
    const int gN   = (N + TB - 1) / TB;                // scan blocks (<=1024)
    const int gN16 = (N * 16 + TB - 1) / TB;           // 16 lanes/node
    const int gNW  = (N + 3) / 4;                      // wave-per-node
    const int gNF  = (int)((NF + TB - 1) / TB);
    const int gNF4 = (int)((NF / 4 + TB - 1) / TB);
    const int gMM  = 3200;                             // matmul grid-stride

    // norm + CSR build
    hipMemsetAsync(cs, 0, (size_t)N * 4, stream);
    hipMemsetAsync(cd, 0, (size_t)N * 4, stream);
    k_counts<<<gE, TB, 0, stream>>>(src, dst, cs, cd, E);
    k_dinv<<<gN, TB, 0, stream>>>(cs, dinv, N);
    k_scan_a<<<gN, TB, 0, stream>>>(cd, rowptr, bsum, N);
    k_scan_b<<<1, 1024, 0, stream>>>(bsum, gN);
    k_scan_c<<<gN, TB, 0, stream>>>(rowptr, wr, bsum, N, E);
    k_fill<<<gE, TB, 0, stream>>>(src, dst, dinv, wr, csr, E);

    // --- Layer 1 (Fin=1) ---
    k_gather1<<<gN16, TB, 0, stream>>>(x,  x,  t1, rowptr, csr, 1.f,  0.f, N);
    k_gather1<<<gN16, TB, 0, stream>>>(t1, x,  t2, rowptr, csr, 2.f, -1.f, N);
    k_gather1<<<gN16, TB, 0, stream>>>(t2, t1, t3, rowptr, csr, 2.f, -1.f, N);
    k_gather1<<<gN16, TB, 0, stream>>>(t3, t2, t4, rowptr, csr, 2.f, -1.f, N);
    k_layer1<<<gNF, TB, 0, stream>>>(x, t1, t2, t3, t4, W1, b1, Pa, Qa, N);

    // --- Layers 2 & 3 (Fin=64) ---
    // h=(Pa,Qa). T1:(Pb,Qb). T2:(Pc,Qa). T3:(Pa,Qb). T4:(Pb,Qa*). h'=(Pc,Qa).
    for (int layer = 0; layer < 2; ++layer) {
        const float* W = (layer == 0) ? W2 : W3;
        const float* b = (layer == 0) ? b2 : b3;
        k_matmul<<<gMM, TB, 0, stream>>>(Pa, W + 0 * 4096, b, ACC, 1, N);
        k_gather64p<<<gNW, TB, 0, stream>>>(Qa, Pa, Pb, Qb, rowptr, csr, 1.f,  0.f, N);
        k_matmul<<<gMM, TB, 0, stream>>>(Pb, W + 1 * 4096, b, ACC, 0, N);
        k_gather64p<<<gNW, TB, 0, stream>>>(Qb, Pa, Pc, Qa, rowptr, csr, 2.f, -1.f, N);
        k_matmul<<<gMM, TB, 0, stream>>>(Pc, W + 2 * 4096, b, ACC, 0, N);
        k_gather64p<<<gNW, TB, 0, stream>>>(Qa, Pb, Pa, Qb, rowptr, csr, 2.f, -1.f, N);
        k_matmul<<<gMM, TB, 0, stream>>>(Pa, W + 3 * 4096, b, ACC, 0, N);
        k_gather64p<<<gNW, TB, 0, stream>>>(Qb, Pc, Pb, Qa, rowptr, csr, 2.f, -1.f, N);
        k_matmul<<<gMM, TB, 0, stream>>>(Pb, W + 4 * 4096, b, ACC, 0, N);
        k_relu2<<<gNF4, TB, 0, stream>>>((const float4*)ACC, (float4*)Pc,
                                         (uint2*)Qa, (int)(NF / 4));
        // next layer input = (Pc, Qa); rotate fp32 pointers
        float* tmp = Pa; Pa = Pc; Pc = Pb; Pb = tmp;
    }

    // --- Final head: h = (Pa, Qa) ---
    k_final<<<gNW, TB, 0, stream>>>(Pa, Wfc, bfc, out, N);
}

// Round 5
// 1389.523 us; speedup vs baseline: 2.7856x; 1.2223x over previous
//
#include <hip/hip_runtime.h>

// ChebNet: 3x ChebConv(K=5) + relu + linear head. N=100000, E=1600000, HID=64.
// R5: 4-edge/wave u64 bf16 gather (16 lanes/edge, 4 feats/lane), rank-based
// atomic-free CSR fill, relu fused into last matmul, dinv fused into scan_c.

#define TB 256

typedef unsigned short u16;
typedef unsigned int u32;

__device__ inline u16 f2bf(float v) {            // RNE fp32 -> bf16
    unsigned u = __float_as_uint(v);
    return (u16)((u + 0x7fffu + ((u >> 16) & 1u)) >> 16);
}

// ---------- pass A: both degree histograms + per-edge rank in dst bucket ----------
__global__ __launch_bounds__(TB) void k_counts(const int* __restrict__ src,
                                               const int* __restrict__ dst,
                                               int* __restrict__ cs,
                                               int* __restrict__ cd,
                                               int* __restrict__ rank, int E) {
    int t = blockIdx.x * TB + threadIdx.x;
    int e0 = t * 4;
    if (e0 + 3 < E) {
        int4 s = *(const int4*)(src + e0);
        int4 d = *(const int4*)(dst + e0);
        atomicAdd(&cs[s.x], 1); atomicAdd(&cs[s.y], 1);
        atomicAdd(&cs[s.z], 1); atomicAdd(&cs[s.w], 1);
        int4 r;
        r.x = atomicAdd(&cd[d.x], 1);
        r.y = atomicAdd(&cd[d.y], 1);
        r.z = atomicAdd(&cd[d.z], 1);
        r.w = atomicAdd(&cd[d.w], 1);
        *(int4*)(rank + e0) = r;
    } else {
        for (int e = e0; e < E; ++e) {
            atomicAdd(&cs[src[e]], 1);
            rank[e] = atomicAdd(&cd[dst[e]], 1);
        }
    }
}

// ---------- CSR build ----------
__global__ __launch_bounds__(TB) void k_scan_a(const int* __restrict__ cnt,
                                               int* __restrict__ excl,
                                               int* __restrict__ bsum, int N) {
    __shared__ int s[TB];
    int t = threadIdx.x;
    int i = blockIdx.x * TB + t;
    int v = (i < N) ? cnt[i] : 0;
    s[t] = v;
    __syncthreads();
    for (int o = 1; o < TB; o <<= 1) {
        int add = (t >= o) ? s[t - o] : 0;
        __syncthreads();
        s[t] += add;
        __syncthreads();
    }
    if (i < N) excl[i] = s[t] - v;
    if (t == TB - 1) bsum[blockIdx.x] = s[t];
}

__global__ __launch_bounds__(1024) void k_scan_b(int* __restrict__ bsum, int nb) {
    __shared__ int s[1024];
    int t = threadIdx.x;
    int v = (t < nb) ? bsum[t] : 0;
    s[t] = v;
    __syncthreads();
    for (int o = 1; o < 1024; o <<= 1) {
        int add = (t >= o) ? s[t - o] : 0;
        __syncthreads();
        s[t] += add;
        __syncthreads();
    }
    if (t < nb) bsum[t] = s[t] - v;
}

// finalize rowptr (+ block offsets), compute dinv from cs; rowptr[N] = E
__global__ __launch_bounds__(TB) void k_scan_c(int* __restrict__ rowptr,
                                               const int* __restrict__ bsum,
                                               const int* __restrict__ cs,
                                               float* __restrict__ dinv,
                                               int N, int E) {
    int i = blockIdx.x * TB + threadIdx.x;
    if (i < N) {
        rowptr[i] += bsum[blockIdx.x];
        int d = cs[i];
        dinv[i] = d > 0 ? rsqrtf((float)d) : 0.f;
    }
    if (i == 0) rowptr[N] = E;
}

// atomic-free fill: pos = rowptr[dst] + rank
__global__ __launch_bounds__(TB) void k_fill(const int* __restrict__ src,
                                             const int* __restrict__ dst,
                                             const int* __restrict__ rank,
                                             const int* __restrict__ rowptr,
                                             const float* __restrict__ dinv,
                                             int2* __restrict__ csr, int E) {
    int e = blockIdx.x * TB + threadIdx.x;
    if (e < E) {
        int s = src[e], d = dst[e];
        float w = -dinv[s] * dinv[d];
        int pos = rowptr[d] + rank[e];
        csr[pos] = make_int2(s, __float_as_int(w));
    }
}

// ---------- layer-1 (Fin=1) props: 16 lanes per node ----------
__global__ __launch_bounds__(TB) void k_gather1(const float* __restrict__ in,
                                                const float* __restrict__ prev,
                                                float* __restrict__ out,
                                                const int* __restrict__ rowptr,
                                                const int2* __restrict__ csr,
                                                float scale, float scale0, int N) {
    int l16 = threadIdx.x & 15;
    int n = blockIdx.x * (TB / 16) + (threadIdx.x >> 4);
    if (n >= N) return;
    int beg = rowptr[n], end = rowptr[n + 1];
    float s = 0.f;
    for (int i = beg + l16; i < end; i += 16) {
        int2 e = csr[i];
        s = fmaf(__int_as_float(e.y), in[e.x], s);
    }
    s += __shfl_down(s, 8, 16);
    s += __shfl_down(s, 4, 16);
    s += __shfl_down(s, 2, 16);
    s += __shfl_down(s, 1, 16);
    if (l16 == 0) out[n] = fmaf(scale, s, scale0 * prev[n]);
}

// Layer 1 combine: h = relu(b1 + sum_k t_k * W1[k]); writes fp32 + bf16
__global__ __launch_bounds__(TB) void k_layer1(const float* __restrict__ x,
                                               const float* __restrict__ t1,
                                               const float* __restrict__ t2,
                                               const float* __restrict__ t3,
                                               const float* __restrict__ t4,
                                               const float* __restrict__ W1,
                                               const float* __restrict__ b1,
                                               float* __restrict__ Hf,
                                               u16* __restrict__ Hb, int N) {
    int tid = blockIdx.x * TB + threadIdx.x;
    if (tid >= N * 64) return;
    int n = tid >> 6, f = tid & 63;
    float v = b1[f];
    v = fmaf(x[n],  W1[f],       v);
    v = fmaf(t1[n], W1[64 + f],  v);
    v = fmaf(t2[n], W1[128 + f], v);
    v = fmaf(t3[n], W1[192 + f], v);
    v = fmaf(t4[n], W1[256 + f], v);
    v = fmaxf(v, 0.f);
    Hf[tid] = v;
    Hb[tid] = f2bf(v);
}

// ---------- prop: bf16 gather, FOUR edges per wave ----------
// quarter q (lane>>4) handles edges beg+q, beg+q+4, ...; lane p (lane&15)
// covers features 4p..4p+3 via one uint2 (u64) load. Quarters combined by
// shfl_xor 16,32. Lanes 0-15 write float4 (fp32) + uint2 (packed bf16).
__global__ __launch_bounds__(TB) void k_gather64q(const u16* __restrict__ inb,
                                                  const float* __restrict__ prev,
                                                  float* __restrict__ outF,
                                                  u16* __restrict__ outB,
                                                  const int* __restrict__ rowptr,
                                                  const int2* __restrict__ csr,
                                                  float scale, float scale0, int N) {
    int lane = threadIdx.x & 63;
    int q = lane >> 4;
    int p = lane & 15;
    int n = blockIdx.x * (TB / 64) + (threadIdx.x >> 6);
    if (n >= N) return;
    int beg = rowptr[n], end = rowptr[n + 1];
    float s0 = 0.f, s1 = 0.f, s2 = 0.f, s3 = 0.f;
    for (int i0 = beg; i0 < end; i0 += 4) {
        int i = i0 + q;
        bool valid = i < end;
        int2 e = csr[valid ? i : beg];
        float w = valid ? __int_as_float(e.y) : 0.f;
        uint2 r = *(const uint2*)(inb + (size_t)e.x * 64 + 4 * p);
        s0 = fmaf(w, __uint_as_float(r.x << 16), s0);
        s1 = fmaf(w, __uint_as_float(r.x & 0xffff0000u), s1);
        s2 = fmaf(w, __uint_as_float(r.y << 16), s2);
        s3 = fmaf(w, __uint_as_float(r.y & 0xffff0000u), s3);
    }
    s0 += __shfl_xor(s0, 16, 64); s0 += __shfl_xor(s0, 32, 64);
    s1 += __shfl_xor(s1, 16, 64); s1 += __shfl_xor(s1, 32, 64);
    s2 += __shfl_xor(s2, 16, 64); s2 += __shfl_xor(s2, 32, 64);
    s3 += __shfl_xor(s3, 16, 64); s3 += __shfl_xor(s3, 32, 64);
    if (lane < 16) {
        size_t o = (size_t)n * 64 + 4 * p;
        float t0 = scale * s0, t1 = scale * s1, t2 = scale * s2, t3 = scale * s3;
        if (scale0 != 0.f) {
            float4 pv = *(const float4*)(prev + o);
            t0 = fmaf(scale0, pv.x, t0);
            t1 = fmaf(scale0, pv.y, t1);
            t2 = fmaf(scale0, pv.z, t2);
            t3 = fmaf(scale0, pv.w, t3);
        }
        *(float4*)(outF + o) = make_float4(t0, t1, t2, t3);
        uint2 b;
        b.x = ((u32)f2bf(t1) << 16) | (u32)f2bf(t0);
        b.y = ((u32)f2bf(t3) << 16) | (u32)f2bf(t2);
        *(uint2*)(outB + o) = b;
    }
}

// ---------- dense: mode 0 = acc += Tx@W; 1 = acc = b + Tx@W;
//                   2 = h = relu(acc + Tx@W) -> hF (fp32) + hB (bf16) ----------
__global__ __launch_bounds__(TB) void k_matmul(const float* __restrict__ Tx,
                                               const float* __restrict__ Wk,
                                               const float* __restrict__ bias,
                                               float* __restrict__ acc,
                                               float* __restrict__ hF,
                                               u16* __restrict__ hB,
                                               int mode, int N) {
    int lane = threadIdx.x & 63;
    int wid = blockIdx.x * (TB / 64) + (threadIdx.x >> 6);
    int nw = gridDim.x * (TB / 64);

    float wcol[64];
#pragma unroll
    for (int j = 0; j < 64; ++j) wcol[j] = Wk[j * 64 + lane];
    float bv = bias[lane];

    for (int n = wid; n < N; n += nw) {
        const float4* row = (const float4*)(Tx + (size_t)n * 64);
        float a = (mode == 1) ? bv : acc[(size_t)n * 64 + lane];
#pragma unroll
        for (int j4 = 0; j4 < 16; ++j4) {
            float4 t = row[j4];
            a = fmaf(t.x, wcol[4 * j4 + 0], a);
            a = fmaf(t.y, wcol[4 * j4 + 1], a);
            a = fmaf(t.z, wcol[4 * j4 + 2], a);
            a = fmaf(t.w, wcol[4 * j4 + 3], a);
        }
        size_t o = (size_t)n * 64 + lane;
        if (mode == 2) {
            float h = fmaxf(a, 0.f);
            hF[o] = h;
            hB[o] = f2bf(h);
        } else {
            acc[o] = a;
        }
    }
}

__global__ __launch_bounds__(TB) void k_final(const float* __restrict__ A,
                                              const float* __restrict__ Wfc,
                                              const float* __restrict__ bfc,
                                              float* __restrict__ out, int N) {
    int lane = threadIdx.x & 63;
    int wid = blockIdx.x * (TB / 64) + (threadIdx.x >> 6);
    if (wid >= N) return;
    float v = A[(size_t)wid * 64 + lane] * Wfc[lane];
#pragma unroll
    for (int o = 32; o > 0; o >>= 1) v += __shfl_down(v, o, 64);
    if (lane == 0) out[wid] = v + bfc[0];
}

extern "C" void kernel_launch(void* const* d_in, const int* in_sizes, int n_in,
                              void* d_out, int out_size, void* d_ws, size_t ws_size,
                              hipStream_t stream) {
    const float* x   = (const float*)d_in[0];
    const int*   ei  = (const int*)d_in[1];
    const float* W1  = (const float*)d_in[2];
    const float* b1  = (const float*)d_in[3];
    const float* W2  = (const float*)d_in[4];
    const float* b2  = (const float*)d_in[5];
    const float* W3  = (const float*)d_in[6];
    const float* b3  = (const float*)d_in[7];
    const float* Wfc = (const float*)d_in[8];
    const float* bfc = (const float*)d_in[9];
    float* out = (float*)d_out;

    const int N = in_sizes[0];
    const int E = in_sizes[1] / 2;
    const int* src = ei;
    const int* dst = ei + E;
    const size_t NF = (size_t)N * 64;

    // workspace layout
    char* p = (char*)d_ws;
    float* Pa  = (float*)p; p += NF * 4;      // fp32 Tx rotation
    float* Pb  = (float*)p; p += NF * 4;
    float* Pc  = (float*)p; p += NF * 4;
    float* ACC = (float*)p; p += NF * 4;
    u16* Qa = (u16*)p; p += NF * 2;           // bf16 Tx rotation
    u16* Qb = (u16*)p; p += NF * 2;
    int2* csr = (int2*)p; p += (size_t)E * 8;
    int* rank = (int*)p; p += (size_t)E * 4;
    float* t1 = (float*)p; p += (size_t)N * 4;
    float* t2 = (float*)p; p += (size_t)N * 4;
    float* t3 = (float*)p; p += (size_t)N * 4;
    float* t4 = (float*)p; p += (size_t)N * 4;
    float* dinv = (float*)p; p += (size_t)N * 4;
    int* cs     = (int*)p; p += (size_t)N * 4;
    int* cd     = (int*)p; p += (size_t)N * 4;
    int* rowptr = (int*)p; p += (size_t)(N + 1) * 4;
    int* bsum   = (int*)p; p += 1024 * 4;

    const int gE   = (E + TB - 1) / TB;
    const int gE4  = ((E + 3) / 4 + TB - 1) / TB;
    const int gN   = (N + TB - 1) / TB;                // scan blocks (<=1024)
    const int gN16 = (N * 16 + TB - 1) / TB;           // 16 lanes/node
    const int gNW  = (N + 3) / 4;                      // wave-per-node
    const int gNF  = (int)((NF + TB - 1) / TB);
    const int gMM  = 3200;                             // matmul grid-stride

    // norm + CSR build
    hipMemsetAsync(cs, 0, (size_t)N * 4, stream);
    hipMemsetAsync(cd, 0, (size_t)N * 4, stream);
    k_counts<<<gE4, TB, 0, stream>>>(src, dst, cs, cd, rank, E);
    k_scan_a<<<gN, TB, 0, stream>>>(cd, rowptr, bsum, N);
    k_scan_b<<<1, 1024, 0, stream>>>(bsum, gN);
    k_scan_c<<<gN, TB, 0, stream>>>(rowptr, bsum, cs, dinv, N, E);
    k_fill<<<gE, TB, 0, stream>>>(src, dst, rank, rowptr, dinv, csr, E);

    // --- Layer 1 (Fin=1) ---
    k_gather1<<<gN16, TB, 0, stream>>>(x,  x,  t1, rowptr, csr, 1.f,  0.f, N);
    k_gather1<<<gN16, TB, 0, stream>>>(t1, x,  t2, rowptr, csr, 2.f, -1.f, N);
    k_gather1<<<gN16, TB, 0, stream>>>(t2, t1, t3, rowptr, csr, 2.f, -1.f, N);
    k_gather1<<<gN16, TB, 0, stream>>>(t3, t2, t4, rowptr, csr, 2.f, -1.f, N);
    k_layer1<<<gNF, TB, 0, stream>>>(x, t1, t2, t3, t4, W1, b1, Pa, Qa, N);

    // --- Layers 2 & 3 (Fin=64) ---
    // h=(Pa,Qa). T1->(Pb,Qb). T2->(Pc,Qa). T3->(Pa,Qb). T4->(Pb,Qa).
    // mm4+relu: h'=(Pc,Qa). Rotate Pa<-Pc.
    for (int layer = 0; layer < 2; ++layer) {
        const float* W = (layer == 0) ? W2 : W3;
        const float* b = (layer == 0) ? b2 : b3;
        k_matmul<<<gMM, TB, 0, stream>>>(Pa, W + 0 * 4096, b, ACC, (float*)0, (u16*)0, 1, N);
        k_gather64q<<<gNW, TB, 0, stream>>>(Qa, Pa, Pb, Qb, rowptr, csr, 1.f,  0.f, N);
        k_matmul<<<gMM, TB, 0, stream>>>(Pb, W + 1 * 4096, b, ACC, (float*)0, (u16*)0, 0, N);
        k_gather64q<<<gNW, TB, 0, stream>>>(Qb, Pa, Pc, Qa, rowptr, csr, 2.f, -1.f, N);
        k_matmul<<<gMM, TB, 0, stream>>>(Pc, W + 2 * 4096, b, ACC, (float*)0, (u16*)0, 0, N);
        k_gather64q<<<gNW, TB, 0, stream>>>(Qa, Pb, Pa, Qb, rowptr, csr, 2.f, -1.f, N);
        k_matmul<<<gMM, TB, 0, stream>>>(Pa, W + 3 * 4096, b, ACC, (float*)0, (u16*)0, 0, N);
        k_gather64q<<<gNW, TB, 0, stream>>>(Qb, Pc, Pb, Qa, rowptr, csr, 2.f, -1.f, N);
        k_matmul<<<gMM, TB, 0, stream>>>(Pb, W + 4 * 4096, b, ACC, Pc, Qa, 2, N);
        // next layer input = (Pc, Qa)
        float* tmp = Pa; Pa = Pc; Pc = tmp;
    }

    // --- Final head: h = (Pa, Qa) ---
    k_final<<<gNW, TB, 0, stream>>>(Pa, Wfc, bfc, out, N);
}

// Round 6
// 1198.433 us; speedup vs baseline: 3.2297x; 1.1594x over previous
//
#include <hip/hip_runtime.h>

// ChebNet: 3x ChebConv(K=5) + relu + linear head. N=100000, E=1600000, HID=64.
// R6: 8-edge/wave uint4 bf16 gather (8 lanes/edge, 8 feats/lane, 2 loads in
// flight), paired matmuls (3 dense kernels/layer), scalar k_counts, rank-based
// atomic-free CSR fill. fp32 recurrence; bf16 only as gather/matmul-R operand.

#define TB 256

typedef unsigned short u16;
typedef unsigned int u32;

__device__ inline u16 f2bf(float v) {            // RNE fp32 -> bf16
    unsigned u = __float_as_uint(v);
    return (u16)((u + 0x7fffu + ((u >> 16) & 1u)) >> 16);
}
__device__ inline float bflo(u32 v) { return __uint_as_float(v << 16); }
__device__ inline float bfhi(u32 v) { return __uint_as_float(v & 0xffff0000u); }

// ---------- pass A: degree histograms + per-edge rank in dst bucket ----------
// scalar 1 edge/thread: max wave parallelism for the atomic write-through
__global__ __launch_bounds__(TB) void k_counts(const int* __restrict__ src,
                                               const int* __restrict__ dst,
                                               int* __restrict__ cs,
                                               int* __restrict__ cd,
                                               int* __restrict__ rank, int E) {
    int e = blockIdx.x * TB + threadIdx.x;
    if (e < E) {
        atomicAdd(&cs[src[e]], 1);
        rank[e] = atomicAdd(&cd[dst[e]], 1);
    }
}

// ---------- CSR build ----------
__global__ __launch_bounds__(TB) void k_scan_a(const int* __restrict__ cnt,
                                               int* __restrict__ excl,
                                               int* __restrict__ bsum, int N) {
    __shared__ int s[TB];
    int t = threadIdx.x;
    int i = blockIdx.x * TB + t;
    int v = (i < N) ? cnt[i] : 0;
    s[t] = v;
    __syncthreads();
    for (int o = 1; o < TB; o <<= 1) {
        int add = (t >= o) ? s[t - o] : 0;
        __syncthreads();
        s[t] += add;
        __syncthreads();
    }
    if (i < N) excl[i] = s[t] - v;
    if (t == TB - 1) bsum[blockIdx.x] = s[t];
}

__global__ __launch_bounds__(1024) void k_scan_b(int* __restrict__ bsum, int nb) {
    __shared__ int s[1024];
    int t = threadIdx.x;
    int v = (t < nb) ? bsum[t] : 0;
    s[t] = v;
    __syncthreads();
    for (int o = 1; o < 1024; o <<= 1) {
        int add = (t >= o) ? s[t - o] : 0;
        __syncthreads();
        s[t] += add;
        __syncthreads();
    }
    if (t < nb) bsum[t] = s[t] - v;
}

// finalize rowptr (+ block offsets), compute dinv from cs; rowptr[N] = E
__global__ __launch_bounds__(TB) void k_scan_c(int* __restrict__ rowptr,
                                               const int* __restrict__ bsum,
                                               const int* __restrict__ cs,
                                               float* __restrict__ dinv,
                                               int N, int E) {
    int i = blockIdx.x * TB + threadIdx.x;
    if (i < N) {
        rowptr[i] += bsum[blockIdx.x];
        int d = cs[i];
        dinv[i] = d > 0 ? rsqrtf((float)d) : 0.f;
    }
    if (i == 0) rowptr[N] = E;
}

// atomic-free fill: pos = rowptr[dst] + rank
__global__ __launch_bounds__(TB) void k_fill(const int* __restrict__ src,
                                             const int* __restrict__ dst,
                                             const int* __restrict__ rank,
                                             const int* __restrict__ rowptr,
                                             const float* __restrict__ dinv,
                                             int2* __restrict__ csr, int E) {
    int e = blockIdx.x * TB + threadIdx.x;
    if (e < E) {
        int s = src[e], d = dst[e];
        float w = -dinv[s] * dinv[d];
        int pos = rowptr[d] + rank[e];
        csr[pos] = make_int2(s, __float_as_int(w));
    }
}

// ---------- layer-1 (Fin=1) props: 16 lanes per node ----------
__global__ __launch_bounds__(TB) void k_gather1(const float* __restrict__ in,
                                                const float* __restrict__ prev,
                                                float* __restrict__ out,
                                                const int* __restrict__ rowptr,
                                                const int2* __restrict__ csr,
                                                float scale, float scale0, int N) {
    int l16 = threadIdx.x & 15;
    int n = blockIdx.x * (TB / 16) + (threadIdx.x >> 4);
    if (n >= N) return;
    int beg = rowptr[n], end = rowptr[n + 1];
    float s = 0.f;
    for (int i = beg + l16; i < end; i += 16) {
        int2 e = csr[i];
        s = fmaf(__int_as_float(e.y), in[e.x], s);
    }
    s += __shfl_down(s, 8, 16);
    s += __shfl_down(s, 4, 16);
    s += __shfl_down(s, 2, 16);
    s += __shfl_down(s, 1, 16);
    if (l16 == 0) out[n] = fmaf(scale, s, scale0 * prev[n]);
}

// Layer 1 combine: h = relu(b1 + sum_k t_k * W1[k]); writes fp32 + bf16
__global__ __launch_bounds__(TB) void k_layer1(const float* __restrict__ x,
                                               const float* __restrict__ t1,
                                               const float* __restrict__ t2,
                                               const float* __restrict__ t3,
                                               const float* __restrict__ t4,
                                               const float* __restrict__ W1,
                                               const float* __restrict__ b1,
                                               float* __restrict__ Hf,
                                               u16* __restrict__ Hb, int N) {
    int tid = blockIdx.x * TB + threadIdx.x;
    if (tid >= N * 64) return;
    int n = tid >> 6, f = tid & 63;
    float v = b1[f];
    v = fmaf(x[n],  W1[f],       v);
    v = fmaf(t1[n], W1[64 + f],  v);
    v = fmaf(t2[n], W1[128 + f], v);
    v = fmaf(t3[n], W1[192 + f], v);
    v = fmaf(t4[n], W1[256 + f], v);
    v = fmaxf(v, 0.f);
    Hf[tid] = v;
    Hb[tid] = f2bf(v);
}

// ---------- prop: bf16 gather, EIGHT edges per wave ----------
// group g = lane>>3 handles edges beg+g, beg+g+8, ... (two per 16-step iter,
// both loads in flight); lane p = lane&7 covers feats 8p..8p+7 via one uint4.
// Butterfly-reduce over groups; lanes 0-7 write 2x float4 + uint4 bf16.
__global__ __launch_bounds__(TB) void k_gather64o(const u16* __restrict__ inb,
                                                  const float* __restrict__ prev,
                                                  float* __restrict__ outF,
                                                  u16* __restrict__ outB,
                                                  const int* __restrict__ rowptr,
                                                  const int2* __restrict__ csr,
                                                  float scale, float scale0,
                                                  int writeF, int N) {
    int lane = threadIdx.x & 63;
    int g = lane >> 3;
    int p = lane & 7;
    int n = blockIdx.x * (TB / 64) + (threadIdx.x >> 6);
    if (n >= N) return;
    int beg = rowptr[n], end = rowptr[n + 1];
    float s0 = 0.f, s1 = 0.f, s2 = 0.f, s3 = 0.f;
    float s4 = 0.f, s5 = 0.f, s6 = 0.f, s7 = 0.f;
    const u16* bp = inb + 8 * p;
    for (int i0 = beg; i0 < end; i0 += 16) {
        int ia = i0 + g, ib = ia + 8;
        bool va = ia < end, vb = ib < end;
        int2 ea = csr[va ? ia : beg];
        int2 eb = csr[vb ? ib : beg];
        uint4 ra = *(const uint4*)(bp + (size_t)ea.x * 64);
        uint4 rb = *(const uint4*)(bp + (size_t)eb.x * 64);
        float wa = va ? __int_as_float(ea.y) : 0.f;
        float wb = vb ? __int_as_float(eb.y) : 0.f;
        s0 = fmaf(wa, bflo(ra.x), s0); s1 = fmaf(wa, bfhi(ra.x), s1);
        s2 = fmaf(wa, bflo(ra.y), s2); s3 = fmaf(wa, bfhi(ra.y), s3);
        s4 = fmaf(wa, bflo(ra.z), s4); s5 = fmaf(wa, bfhi(ra.z), s5);
        s6 = fmaf(wa, bflo(ra.w), s6); s7 = fmaf(wa, bfhi(ra.w), s7);
        s0 = fmaf(wb, bflo(rb.x), s0); s1 = fmaf(wb, bfhi(rb.x), s1);
        s2 = fmaf(wb, bflo(rb.y), s2); s3 = fmaf(wb, bfhi(rb.y), s3);
        s4 = fmaf(wb, bflo(rb.z), s4); s5 = fmaf(wb, bfhi(rb.z), s5);
        s6 = fmaf(wb, bflo(rb.w), s6); s7 = fmaf(wb, bfhi(rb.w), s7);
    }
#pragma unroll
    for (int o = 8; o < 64; o <<= 1) {
        s0 += __shfl_xor(s0, o, 64); s1 += __shfl_xor(s1, o, 64);
        s2 += __shfl_xor(s2, o, 64); s3 += __shfl_xor(s3, o, 64);
        s4 += __shfl_xor(s4, o, 64); s5 += __shfl_xor(s5, o, 64);
        s6 += __shfl_xor(s6, o, 64); s7 += __shfl_xor(s7, o, 64);
    }
    if (lane < 8) {
        size_t o = (size_t)n * 64 + 8 * p;
        float t0 = scale * s0, t1 = scale * s1, t2 = scale * s2, t3 = scale * s3;
        float t4 = scale * s4, t5 = scale * s5, t6 = scale * s6, t7 = scale * s7;
        if (scale0 != 0.f) {
            float4 p0 = *(const float4*)(prev + o);
            float4 p1 = *(const float4*)(prev + o + 4);
            t0 = fmaf(scale0, p0.x, t0); t1 = fmaf(scale0, p0.y, t1);
            t2 = fmaf(scale0, p0.z, t2); t3 = fmaf(scale0, p0.w, t3);
            t4 = fmaf(scale0, p1.x, t4); t5 = fmaf(scale0, p1.y, t5);
            t6 = fmaf(scale0, p1.z, t6); t7 = fmaf(scale0, p1.w, t7);
        }
        if (writeF) {
            *(float4*)(outF + o)     = make_float4(t0, t1, t2, t3);
            *(float4*)(outF + o + 4) = make_float4(t4, t5, t6, t7);
        }
        uint4 b;
        b.x = ((u32)f2bf(t1) << 16) | (u32)f2bf(t0);
        b.y = ((u32)f2bf(t3) << 16) | (u32)f2bf(t2);
        b.z = ((u32)f2bf(t5) << 16) | (u32)f2bf(t4);
        b.w = ((u32)f2bf(t7) << 16) | (u32)f2bf(t6);
        *(uint4*)(outB + o) = b;
    }
}

// ---------- paired dense: acc (=|+=) [b +] TxA@Wa + TxB@Wb ----------
__global__ __launch_bounds__(TB) void k_matmul2(const float* __restrict__ TxA,
                                                const float* __restrict__ TxB,
                                                const float* __restrict__ Wa,
                                                const float* __restrict__ Wb,
                                                const float* __restrict__ bias,
                                                float* __restrict__ acc,
                                                int initFlag, int N) {
    int lane = threadIdx.x & 63;
    int wid = blockIdx.x * (TB / 64) + (threadIdx.x >> 6);
    int nw = gridDim.x * (TB / 64);

    float wa[64], wb[64];
#pragma unroll
    for (int j = 0; j < 64; ++j) wa[j] = Wa[j * 64 + lane];
#pragma unroll
    for (int j = 0; j < 64; ++j) wb[j] = Wb[j * 64 + lane];
    float bv = bias[lane];

    for (int n = wid; n < N; n += nw) {
        size_t o = (size_t)n * 64;
        float a = initFlag ? bv : acc[o + lane];
        const float4* ra = (const float4*)(TxA + o);
        const float4* rb = (const float4*)(TxB + o);
#pragma unroll
        for (int j4 = 0; j4 < 16; ++j4) {
            float4 t = ra[j4];
            a = fmaf(t.x, wa[4 * j4 + 0], a);
            a = fmaf(t.y, wa[4 * j4 + 1], a);
            a = fmaf(t.z, wa[4 * j4 + 2], a);
            a = fmaf(t.w, wa[4 * j4 + 3], a);
        }
#pragma unroll
        for (int j4 = 0; j4 < 16; ++j4) {
            float4 t = rb[j4];
            a = fmaf(t.x, wb[4 * j4 + 0], a);
            a = fmaf(t.y, wb[4 * j4 + 1], a);
            a = fmaf(t.z, wb[4 * j4 + 2], a);
            a = fmaf(t.w, wb[4 * j4 + 3], a);
        }
        acc[o + lane] = a;
    }
}

// ---------- final dense of a layer: h = relu(acc + bf(Qx)@W) -> hF, hB ----------
__global__ __launch_bounds__(TB) void k_matmulR(const u16* __restrict__ Qx,
                                                const float* __restrict__ W,
                                                const float* __restrict__ acc,
                                                float* __restrict__ hF,
                                                u16* __restrict__ hB, int N) {
    int lane = threadIdx.x & 63;
    int wid = blockIdx.x * (TB / 64) + (threadIdx.x >> 6);
    int nw = gridDim.x * (TB / 64);

    float wcol[64];
#pragma unroll
    for (int j = 0; j < 64; ++j) wcol[j] = W[j * 64 + lane];

    for (int n = wid; n < N; n += nw) {
        size_t o = (size_t)n * 64;
        float a = acc[o + lane];
        const uint4* row = (const uint4*)(Qx + o);
#pragma unroll
        for (int j8 = 0; j8 < 8; ++j8) {
            uint4 r = row[j8];
            a = fmaf(bflo(r.x), wcol[8 * j8 + 0], a);
            a = fmaf(bfhi(r.x), wcol[8 * j8 + 1], a);
            a = fmaf(bflo(r.y), wcol[8 * j8 + 2], a);
            a = fmaf(bfhi(r.y), wcol[8 * j8 + 3], a);
            a = fmaf(bflo(r.z), wcol[8 * j8 + 4], a);
            a = fmaf(bfhi(r.z), wcol[8 * j8 + 5], a);
            a = fmaf(bflo(r.w), wcol[8 * j8 + 6], a);
            a = fmaf(bfhi(r.w), wcol[8 * j8 + 7], a);
        }
        float h = fmaxf(a, 0.f);
        hF[o + lane] = h;
        hB[o + lane] = f2bf(h);
    }
}

__global__ __launch_bounds__(TB) void k_final(const float* __restrict__ A,
                                              const float* __restrict__ Wfc,
                                              const float* __restrict__ bfc,
                                              float* __restrict__ out, int N) {
    int lane = threadIdx.x & 63;
    int wid = blockIdx.x * (TB / 64) + (threadIdx.x >> 6);
    if (wid >= N) return;
    float v = A[(size_t)wid * 64 + lane] * Wfc[lane];
#pragma unroll
    for (int o = 32; o > 0; o >>= 1) v += __shfl_down(v, o, 64);
    if (lane == 0) out[wid] = v + bfc[0];
}

extern "C" void kernel_launch(void* const* d_in, const int* in_sizes, int n_in,
                              void* d_out, int out_size, void* d_ws, size_t ws_size,
                              hipStream_t stream) {
    const float* x   = (const float*)d_in[0];
    const int*   ei  = (const int*)d_in[1];
    const float* W1  = (const float*)d_in[2];
    const float* b1  = (const float*)d_in[3];
    const float* W2  = (const float*)d_in[4];
    const float* b2  = (const float*)d_in[5];
    const float* W3  = (const float*)d_in[6];
    const float* b3  = (const float*)d_in[7];
    const float* Wfc = (const float*)d_in[8];
    const float* bfc = (const float*)d_in[9];
    float* out = (float*)d_out;

    const int N = in_sizes[0];
    const int E = in_sizes[1] / 2;
    const int* src = ei;
    const int* dst = ei + E;
    const size_t NF = (size_t)N * 64;

    // workspace layout
    char* p = (char*)d_ws;
    float* Pa  = (float*)p; p += NF * 4;      // fp32 Tx rotation
    float* Pb  = (float*)p; p += NF * 4;
    float* Pc  = (float*)p; p += NF * 4;
    float* ACC = (float*)p; p += NF * 4;
    u16* Qa = (u16*)p; p += NF * 2;           // bf16 Tx rotation
    u16* Qb = (u16*)p; p += NF * 2;
    int2* csr = (int2*)p; p += (size_t)E * 8;
    int* rank = (int*)p; p += (size_t)E * 4;
    float* t1 = (float*)p; p += (size_t)N * 4;
    float* t2 = (float*)p; p += (size_t)N * 4;
    float* t3 = (float*)p; p += (size_t)N * 4;
    float* t4 = (float*)p; p += (size_t)N * 4;
    float* dinv = (float*)p; p += (size_t)N * 4;
    int* cs     = (int*)p; p += (size_t)N * 4;
    int* cd     = (int*)p; p += (size_t)N * 4;
    int* rowptr = (int*)p; p += (size_t)(N + 1) * 4;
    int* bsum   = (int*)p; p += 1024 * 4;

    const int gE   = (E + TB - 1) / TB;
    const int gN   = (N + TB - 1) / TB;                // scan blocks (<=1024)
    const int gN16 = (N * 16 + TB - 1) / TB;           // 16 lanes/node
    const int gNW  = (N + 3) / 4;                      // wave-per-node
    const int gNF  = (int)((NF + TB - 1) / TB);
    const int gMM  = 3200;                             // dense grid-stride

    // norm + CSR build
    hipMemsetAsync(cs, 0, (size_t)N * 4, stream);
    hipMemsetAsync(cd, 0, (size_t)N * 4, stream);
    k_counts<<<gE, TB, 0, stream>>>(src, dst, cs, cd, rank, E);
    k_scan_a<<<gN, TB, 0, stream>>>(cd, rowptr, bsum, N);
    k_scan_b<<<1, 1024, 0, stream>>>(bsum, gN);
    k_scan_c<<<gN, TB, 0, stream>>>(rowptr, bsum, cs, dinv, N, E);
    k_fill<<<gE, TB, 0, stream>>>(src, dst, rank, rowptr, dinv, csr, E);

    // --- Layer 1 (Fin=1) ---
    k_gather1<<<gN16, TB, 0, stream>>>(x,  x,  t1, rowptr, csr, 1.f,  0.f, N);
    k_gather1<<<gN16, TB, 0, stream>>>(t1, x,  t2, rowptr, csr, 2.f, -1.f, N);
    k_gather1<<<gN16, TB, 0, stream>>>(t2, t1, t3, rowptr, csr, 2.f, -1.f, N);
    k_gather1<<<gN16, TB, 0, stream>>>(t3, t2, t4, rowptr, csr, 2.f, -1.f, N);
    k_layer1<<<gNF, TB, 0, stream>>>(x, t1, t2, t3, t4, W1, b1, Pa, Qa, N);

    // --- Layers 2 & 3 (Fin=64) ---
    // h=(Pa,Qa).
    //  gT1: in=Qa           -> (Pb,Qb)
    //  mm01: ACC = b + Pa@W0 + Pb@W1
    //  gT2: in=Qb, prev=Pa  -> (Pc,Qa)
    //  gT3: in=Qa, prev=Pb  -> (Pa,Qb)
    //  mm23: ACC += Pc@W2 + Pa@W3
    //  gT4: in=Qb, prev=Pc  -> (--,Qa)     [fp32 skipped]
    //  mmR: h' = relu(ACC + Qa@W4) -> (Pc,Qb)
    //  swap Pa<->Pc, Qa<->Qb.
    for (int layer = 0; layer < 2; ++layer) {
        const float* W = (layer == 0) ? W2 : W3;
        const float* b = (layer == 0) ? b2 : b3;
        k_gather64o<<<gNW, TB, 0, stream>>>(Qa, Pa, Pb, Qb, rowptr, csr, 1.f,  0.f, 1, N);
        k_matmul2<<<gMM, TB, 0, stream>>>(Pa, Pb, W + 0 * 4096, W + 1 * 4096, b, ACC, 1, N);
        k_gather64o<<<gNW, TB, 0, stream>>>(Qb, Pa, Pc, Qa, rowptr, csr, 2.f, -1.f, 1, N);
        k_gather64o<<<gNW, TB, 0, stream>>>(Qa, Pb, Pa, Qb, rowptr, csr, 2.f, -1.f, 1, N);
        k_matmul2<<<gMM, TB, 0, stream>>>(Pc, Pa, W + 2 * 4096, W + 3 * 4096, b, ACC, 0, N);
        k_gather64o<<<gNW, TB, 0, stream>>>(Qb, Pc, (float*)0, Qa, rowptr, csr, 2.f, -1.f, 0, N);
        k_matmulR<<<gMM, TB, 0, stream>>>(Qa, W + 4 * 4096, ACC, Pc, Qb, N);
        float* tp = Pa; Pa = Pc; Pc = tp;
        u16* tq = Qa; Qa = Qb; Qb = tq;
    }

    // --- Final head: h = (Pa, Qa) ---
    k_final<<<gNW, TB, 0, stream>>>(Pa, Wfc, bfc, out, N);
}

// Round 7
// 1071.483 us; speedup vs baseline: 3.6124x; 1.1185x over previous
//
#include <hip/hip_runtime.h>

// ChebNet: 3x ChebConv(K=5) + relu + linear head. N=100000, E=1600000, HID=64.
// R7: ALL-bf16 activations (fp32 only in accumulators/ACC). Gathers read prev
// bf16 + write bf16 only; matmuls consume bf16 via uint4 unpack; 8-edge/wave
// gather; rank-based atomic-free CSR fill.

#define TB 256

typedef unsigned short u16;
typedef unsigned int u32;

__device__ inline u16 f2bf(float v) {            // RNE fp32 -> bf16
    unsigned u = __float_as_uint(v);
    return (u16)((u + 0x7fffu + ((u >> 16) & 1u)) >> 16);
}
__device__ inline float bflo(u32 v) { return __uint_as_float(v << 16); }
__device__ inline float bfhi(u32 v) { return __uint_as_float(v & 0xffff0000u); }
__device__ inline float bf2f(u16 v) { return __uint_as_float(((u32)v) << 16); }

// ---------- pass A: degree histograms + per-edge rank in dst bucket ----------
__global__ __launch_bounds__(TB) void k_counts(const int* __restrict__ src,
                                               const int* __restrict__ dst,
                                               int* __restrict__ cs,
                                               int* __restrict__ cd,
                                               int* __restrict__ rank, int E) {
    int e = blockIdx.x * TB + threadIdx.x;
    if (e < E) {
        atomicAdd(&cs[src[e]], 1);
        rank[e] = atomicAdd(&cd[dst[e]], 1);
    }
}

// ---------- CSR build ----------
__global__ __launch_bounds__(TB) void k_scan_a(const int* __restrict__ cnt,
                                               int* __restrict__ excl,
                                               int* __restrict__ bsum, int N) {
    __shared__ int s[TB];
    int t = threadIdx.x;
    int i = blockIdx.x * TB + t;
    int v = (i < N) ? cnt[i] : 0;
    s[t] = v;
    __syncthreads();
    for (int o = 1; o < TB; o <<= 1) {
        int add = (t >= o) ? s[t - o] : 0;
        __syncthreads();
        s[t] += add;
        __syncthreads();
    }
    if (i < N) excl[i] = s[t] - v;
    if (t == TB - 1) bsum[blockIdx.x] = s[t];
}

__global__ __launch_bounds__(1024) void k_scan_b(int* __restrict__ bsum, int nb) {
    __shared__ int s[1024];
    int t = threadIdx.x;
    int v = (t < nb) ? bsum[t] : 0;
    s[t] = v;
    __syncthreads();
    for (int o = 1; o < 1024; o <<= 1) {
        int add = (t >= o) ? s[t - o] : 0;
        __syncthreads();
        s[t] += add;
        __syncthreads();
    }
    if (t < nb) bsum[t] = s[t] - v;
}

__global__ __launch_bounds__(TB) void k_scan_c(int* __restrict__ rowptr,
                                               const int* __restrict__ bsum,
                                               const int* __restrict__ cs,
                                               float* __restrict__ dinv,
                                               int N, int E) {
    int i = blockIdx.x * TB + threadIdx.x;
    if (i < N) {
        rowptr[i] += bsum[blockIdx.x];
        int d = cs[i];
        dinv[i] = d > 0 ? rsqrtf((float)d) : 0.f;
    }
    if (i == 0) rowptr[N] = E;
}

__global__ __launch_bounds__(TB) void k_fill(const int* __restrict__ src,
                                             const int* __restrict__ dst,
                                             const int* __restrict__ rank,
                                             const int* __restrict__ rowptr,
                                             const float* __restrict__ dinv,
                                             int2* __restrict__ csr, int E) {
    int e = blockIdx.x * TB + threadIdx.x;
    if (e < E) {
        int s = src[e], d = dst[e];
        float w = -dinv[s] * dinv[d];
        int pos = rowptr[d] + rank[e];
        csr[pos] = make_int2(s, __float_as_int(w));
    }
}

// ---------- layer-1 (Fin=1) props: 16 lanes per node ----------
__global__ __launch_bounds__(TB) void k_gather1(const float* __restrict__ in,
                                                const float* __restrict__ prev,
                                                float* __restrict__ out,
                                                const int* __restrict__ rowptr,
                                                const int2* __restrict__ csr,
                                                float scale, float scale0, int N) {
    int l16 = threadIdx.x & 15;
    int n = blockIdx.x * (TB / 16) + (threadIdx.x >> 4);
    if (n >= N) return;
    int beg = rowptr[n], end = rowptr[n + 1];
    float s = 0.f;
    for (int i = beg + l16; i < end; i += 16) {
        int2 e = csr[i];
        s = fmaf(__int_as_float(e.y), in[e.x], s);
    }
    s += __shfl_down(s, 8, 16);
    s += __shfl_down(s, 4, 16);
    s += __shfl_down(s, 2, 16);
    s += __shfl_down(s, 1, 16);
    if (l16 == 0) out[n] = fmaf(scale, s, scale0 * prev[n]);
}

// Layer 1 combine: h = relu(b1 + sum_k t_k * W1[k]) -> bf16
__global__ __launch_bounds__(TB) void k_layer1(const float* __restrict__ x,
                                               const float* __restrict__ t1,
                                               const float* __restrict__ t2,
                                               const float* __restrict__ t3,
                                               const float* __restrict__ t4,
                                               const float* __restrict__ W1,
                                               const float* __restrict__ b1,
                                               u16* __restrict__ Hb, int N) {
    int tid = blockIdx.x * TB + threadIdx.x;
    if (tid >= N * 64) return;
    int n = tid >> 6, f = tid & 63;
    float v = b1[f];
    v = fmaf(x[n],  W1[f],       v);
    v = fmaf(t1[n], W1[64 + f],  v);
    v = fmaf(t2[n], W1[128 + f], v);
    v = fmaf(t3[n], W1[192 + f], v);
    v = fmaf(t4[n], W1[256 + f], v);
    Hb[tid] = f2bf(fmaxf(v, 0.f));
}

// ---------- prop: bf16 gather, EIGHT edges per wave, bf16 in/out ----------
// group g = lane>>3 handles edges beg+g, beg+g+8, ...; lane p = lane&7 covers
// feats 8p..8p+7 via one uint4. Butterfly over groups; lanes 0-7 write uint4.
__global__ __launch_bounds__(TB) void k_gather64o(const u16* __restrict__ inb,
                                                  const u16* __restrict__ prevb,
                                                  u16* __restrict__ outB,
                                                  const int* __restrict__ rowptr,
                                                  const int2* __restrict__ csr,
                                                  float scale, float scale0, int N) {
    int lane = threadIdx.x & 63;
    int g = lane >> 3;
    int p = lane & 7;
    int n = blockIdx.x * (TB / 64) + (threadIdx.x >> 6);
    if (n >= N) return;
    int beg = rowptr[n], end = rowptr[n + 1];
    float s0 = 0.f, s1 = 0.f, s2 = 0.f, s3 = 0.f;
    float s4 = 0.f, s5 = 0.f, s6 = 0.f, s7 = 0.f;
    const u16* bp = inb + 8 * p;
    for (int i0 = beg; i0 < end; i0 += 16) {
        int ia = i0 + g, ib = ia + 8;
        bool va = ia < end, vb = ib < end;
        int2 ea = csr[va ? ia : beg];
        int2 eb = csr[vb ? ib : beg];
        uint4 ra = *(const uint4*)(bp + (size_t)ea.x * 64);
        uint4 rb = *(const uint4*)(bp + (size_t)eb.x * 64);
        float wa = va ? __int_as_float(ea.y) : 0.f;
        float wb = vb ? __int_as_float(eb.y) : 0.f;
        s0 = fmaf(wa, bflo(ra.x), s0); s1 = fmaf(wa, bfhi(ra.x), s1);
        s2 = fmaf(wa, bflo(ra.y), s2); s3 = fmaf(wa, bfhi(ra.y), s3);
        s4 = fmaf(wa, bflo(ra.z), s4); s5 = fmaf(wa, bfhi(ra.z), s5);
        s6 = fmaf(wa, bflo(ra.w), s6); s7 = fmaf(wa, bfhi(ra.w), s7);
        s0 = fmaf(wb, bflo(rb.x), s0); s1 = fmaf(wb, bfhi(rb.x), s1);
        s2 = fmaf(wb, bflo(rb.y), s2); s3 = fmaf(wb, bfhi(rb.y), s3);
        s4 = fmaf(wb, bflo(rb.z), s4); s5 = fmaf(wb, bfhi(rb.z), s5);
        s6 = fmaf(wb, bflo(rb.w), s6); s7 = fmaf(wb, bfhi(rb.w), s7);
    }
#pragma unroll
    for (int o = 8; o < 64; o <<= 1) {
        s0 += __shfl_xor(s0, o, 64); s1 += __shfl_xor(s1, o, 64);
        s2 += __shfl_xor(s2, o, 64); s3 += __shfl_xor(s3, o, 64);
        s4 += __shfl_xor(s4, o, 64); s5 += __shfl_xor(s5, o, 64);
        s6 += __shfl_xor(s6, o, 64); s7 += __shfl_xor(s7, o, 64);
    }
    if (lane < 8) {
        size_t o = (size_t)n * 64 + 8 * p;
        float t0 = scale * s0, t1 = scale * s1, t2 = scale * s2, t3 = scale * s3;
        float t4 = scale * s4, t5 = scale * s5, t6 = scale * s6, t7 = scale * s7;
        if (scale0 != 0.f) {
            uint4 pv = *(const uint4*)(prevb + o);
            t0 = fmaf(scale0, bflo(pv.x), t0); t1 = fmaf(scale0, bfhi(pv.x), t1);
            t2 = fmaf(scale0, bflo(pv.y), t2); t3 = fmaf(scale0, bfhi(pv.y), t3);
            t4 = fmaf(scale0, bflo(pv.z), t4); t5 = fmaf(scale0, bfhi(pv.z), t5);
            t6 = fmaf(scale0, bflo(pv.w), t6); t7 = fmaf(scale0, bfhi(pv.w), t7);
        }
        uint4 b;
        b.x = ((u32)f2bf(t1) << 16) | (u32)f2bf(t0);
        b.y = ((u32)f2bf(t3) << 16) | (u32)f2bf(t2);
        b.z = ((u32)f2bf(t5) << 16) | (u32)f2bf(t4);
        b.w = ((u32)f2bf(t7) << 16) | (u32)f2bf(t6);
        *(uint4*)(outB + o) = b;
    }
}

// ---------- paired dense (bf16 inputs): acc (=|+=) [b +] QA@Wa + QB@Wb ----------
__global__ __launch_bounds__(TB) void k_matmul2(const u16* __restrict__ QA,
                                                const u16* __restrict__ QB,
                                                const float* __restrict__ Wa,
                                                const float* __restrict__ Wb,
                                                const float* __restrict__ bias,
                                                float* __restrict__ acc,
                                                int initFlag, int N) {
    int lane = threadIdx.x & 63;
    int wid = blockIdx.x * (TB / 64) + (threadIdx.x >> 6);
    int nw = gridDim.x * (TB / 64);

    float wa[64], wb[64];
#pragma unroll
    for (int j = 0; j < 64; ++j) wa[j] = Wa[j * 64 + lane];
#pragma unroll
    for (int j = 0; j < 64; ++j) wb[j] = Wb[j * 64 + lane];
    float bv = bias[lane];

    for (int n = wid; n < N; n += nw) {
        size_t o = (size_t)n * 64;
        float a = initFlag ? bv : acc[o + lane];
        const uint4* ra = (const uint4*)(QA + o);
        const uint4* rb = (const uint4*)(QB + o);
#pragma unroll
        for (int j8 = 0; j8 < 8; ++j8) {
            uint4 r = ra[j8];
            a = fmaf(bflo(r.x), wa[8 * j8 + 0], a);
            a = fmaf(bfhi(r.x), wa[8 * j8 + 1], a);
            a = fmaf(bflo(r.y), wa[8 * j8 + 2], a);
            a = fmaf(bfhi(r.y), wa[8 * j8 + 3], a);
            a = fmaf(bflo(r.z), wa[8 * j8 + 4], a);
            a = fmaf(bfhi(r.z), wa[8 * j8 + 5], a);
            a = fmaf(bflo(r.w), wa[8 * j8 + 6], a);
            a = fmaf(bfhi(r.w), wa[8 * j8 + 7], a);
        }
#pragma unroll
        for (int j8 = 0; j8 < 8; ++j8) {
            uint4 r = rb[j8];
            a = fmaf(bflo(r.x), wb[8 * j8 + 0], a);
            a = fmaf(bfhi(r.x), wb[8 * j8 + 1], a);
            a = fmaf(bflo(r.y), wb[8 * j8 + 2], a);
            a = fmaf(bfhi(r.y), wb[8 * j8 + 3], a);
            a = fmaf(bflo(r.z), wb[8 * j8 + 4], a);
            a = fmaf(bfhi(r.z), wb[8 * j8 + 5], a);
            a = fmaf(bflo(r.w), wb[8 * j8 + 6], a);
            a = fmaf(bfhi(r.w), wb[8 * j8 + 7], a);
        }
        acc[o + lane] = a;
    }
}

// ---------- final dense of a layer: h = relu(acc + bf(Qx)@W) -> bf16 ----------
__global__ __launch_bounds__(TB) void k_matmulR(const u16* __restrict__ Qx,
                                                const float* __restrict__ W,
                                                const float* __restrict__ acc,
                                                u16* __restrict__ hB, int N) {
    int lane = threadIdx.x & 63;
    int wid = blockIdx.x * (TB / 64) + (threadIdx.x >> 6);
    int nw = gridDim.x * (TB / 64);

    float wcol[64];
#pragma unroll
    for (int j = 0; j < 64; ++j) wcol[j] = W[j * 64 + lane];

    for (int n = wid; n < N; n += nw) {
        size_t o = (size_t)n * 64;
        float a = acc[o + lane];
        const uint4* row = (const uint4*)(Qx + o);
#pragma unroll
        for (int j8 = 0; j8 < 8; ++j8) {
            uint4 r = row[j8];
            a = fmaf(bflo(r.x), wcol[8 * j8 + 0], a);
            a = fmaf(bfhi(r.x), wcol[8 * j8 + 1], a);
            a = fmaf(bflo(r.y), wcol[8 * j8 + 2], a);
            a = fmaf(bfhi(r.y), wcol[8 * j8 + 3], a);
            a = fmaf(bflo(r.z), wcol[8 * j8 + 4], a);
            a = fmaf(bfhi(r.z), wcol[8 * j8 + 5], a);
            a = fmaf(bflo(r.w), wcol[8 * j8 + 6], a);
            a = fmaf(bfhi(r.w), wcol[8 * j8 + 7], a);
        }
        hB[o + lane] = f2bf(fmaxf(a, 0.f));
    }
}

// ---------- final head: out = bfc + h @ Wfc (h bf16) ----------
__global__ __launch_bounds__(TB) void k_final(const u16* __restrict__ A,
                                              const float* __restrict__ Wfc,
                                              const float* __restrict__ bfc,
                                              float* __restrict__ out, int N) {
    int lane = threadIdx.x & 63;
    int wid = blockIdx.x * (TB / 64) + (threadIdx.x >> 6);
    if (wid >= N) return;
    float v = bf2f(A[(size_t)wid * 64 + lane]) * Wfc[lane];
#pragma unroll
    for (int o = 32; o > 0; o >>= 1) v += __shfl_down(v, o, 64);
    if (lane == 0) out[wid] = v + bfc[0];
}

extern "C" void kernel_launch(void* const* d_in, const int* in_sizes, int n_in,
                              void* d_out, int out_size, void* d_ws, size_t ws_size,
                              hipStream_t stream) {
    const float* x   = (const float*)d_in[0];
    const int*   ei  = (const int*)d_in[1];
    const float* W1  = (const float*)d_in[2];
    const float* b1  = (const float*)d_in[3];
    const float* W2  = (const float*)d_in[4];
    const float* b2  = (const float*)d_in[5];
    const float* W3  = (const float*)d_in[6];
    const float* b3  = (const float*)d_in[7];
    const float* Wfc = (const float*)d_in[8];
    const float* bfc = (const float*)d_in[9];
    float* out = (float*)d_out;

    const int N = in_sizes[0];
    const int E = in_sizes[1] / 2;
    const int* src = ei;
    const int* dst = ei + E;
    const size_t NF = (size_t)N * 64;

    // workspace layout
    char* p = (char*)d_ws;
    float* ACC = (float*)p; p += NF * 4;
    u16* QA = (u16*)p; p += NF * 2;           // bf16 activation rotation (4 bufs)
    u16* QB = (u16*)p; p += NF * 2;
    u16* QC = (u16*)p; p += NF * 2;
    u16* QD = (u16*)p; p += NF * 2;
    int2* csr = (int2*)p; p += (size_t)E * 8;
    int* rank = (int*)p; p += (size_t)E * 4;
    float* t1 = (float*)p; p += (size_t)N * 4;
    float* t2 = (float*)p; p += (size_t)N * 4;
    float* t3 = (float*)p; p += (size_t)N * 4;
    float* t4 = (float*)p; p += (size_t)N * 4;
    float* dinv = (float*)p; p += (size_t)N * 4;
    int* cs     = (int*)p; p += (size_t)N * 4;
    int* cd     = (int*)p; p += (size_t)N * 4;
    int* rowptr = (int*)p; p += (size_t)(N + 1) * 4;
    int* bsum   = (int*)p; p += 1024 * 4;

    const int gE   = (E + TB - 1) / TB;
    const int gN   = (N + TB - 1) / TB;                // scan blocks (<=1024)
    const int gN16 = (N * 16 + TB - 1) / TB;           // 16 lanes/node
    const int gNW  = (N + 3) / 4;                      // wave-per-node
    const int gNF  = (int)((NF + TB - 1) / TB);
    const int gMM  = 3200;                             // dense grid-stride

    // norm + CSR build
    hipMemsetAsync(cs, 0, (size_t)N * 4, stream);
    hipMemsetAsync(cd, 0, (size_t)N * 4, stream);
    k_counts<<<gE, TB, 0, stream>>>(src, dst, cs, cd, rank, E);
    k_scan_a<<<gN, TB, 0, stream>>>(cd, rowptr, bsum, N);
    k_scan_b<<<1, 1024, 0, stream>>>(bsum, gN);
    k_scan_c<<<gN, TB, 0, stream>>>(rowptr, bsum, cs, dinv, N, E);
    k_fill<<<gE, TB, 0, stream>>>(src, dst, rank, rowptr, dinv, csr, E);

    // --- Layer 1 (Fin=1) ---
    k_gather1<<<gN16, TB, 0, stream>>>(x,  x,  t1, rowptr, csr, 1.f,  0.f, N);
    k_gather1<<<gN16, TB, 0, stream>>>(t1, x,  t2, rowptr, csr, 2.f, -1.f, N);
    k_gather1<<<gN16, TB, 0, stream>>>(t2, t1, t3, rowptr, csr, 2.f, -1.f, N);
    k_gather1<<<gN16, TB, 0, stream>>>(t3, t2, t4, rowptr, csr, 2.f, -1.f, N);
    k_layer1<<<gNF, TB, 0, stream>>>(x, t1, t2, t3, t4, W1, b1, QA, N);

    // --- Layers 2 & 3 (Fin=64), all-bf16 activations ---
    // h=A. gT1: A->B. mm01(A,B). gT2: in=B prev=A -> C. gT3: in=C prev=B -> D.
    // mm23(C,D). gT4: in=D prev=C -> A. mmR(A) -> h'=B. Next: h=B, free C,D,A.
    u16 *A = QA, *B = QB, *C = QC, *D = QD;
    for (int layer = 0; layer < 2; ++layer) {
        const float* W = (layer == 0) ? W2 : W3;
        const float* b = (layer == 0) ? b2 : b3;
        k_gather64o<<<gNW, TB, 0, stream>>>(A, A, B, rowptr, csr, 1.f,  0.f, N);
        k_matmul2<<<gMM, TB, 0, stream>>>(A, B, W + 0 * 4096, W + 1 * 4096, b, ACC, 1, N);
        k_gather64o<<<gNW, TB, 0, stream>>>(B, A, C, rowptr, csr, 2.f, -1.f, N);
        k_gather64o<<<gNW, TB, 0, stream>>>(C, B, D, rowptr, csr, 2.f, -1.f, N);
        k_matmul2<<<gMM, TB, 0, stream>>>(C, D, W + 2 * 4096, W + 3 * 4096, b, ACC, 0, N);
        k_gather64o<<<gNW, TB, 0, stream>>>(D, C, A, rowptr, csr, 2.f, -1.f, N);
        k_matmulR<<<gMM, TB, 0, stream>>>(A, W + 4 * 4096, ACC, B, N);
        // rotate: new h = B; reuse old A,C,D as scratch
        u16* nh = B; B = C; C = D; D = A; A = nh;
    }

    // --- Final head: h = A (bf16) ---
    k_final<<<gNW, TB, 0, stream>>>(A, Wfc, bfc, out, N);
}

// Round 8
// 1064.966 us; speedup vs baseline: 3.6345x; 1.0061x over previous
//
#include <hip/hip_runtime.h>

// ChebNet: 3x ChebConv(K=5) + relu + linear head. N=100000, E=1600000, HID=64.
// R8: 4-deep MLP gather (step-32, 4 clamped slots/group), line-padded cd
// histogram (kills RMW line contention on the rank-returning atomic).
// All-bf16 activations, fp32 accumulators; rank-based atomic-free CSR fill.

#define TB 256

typedef unsigned short u16;
typedef unsigned int u32;

__device__ inline u16 f2bf(float v) {            // RNE fp32 -> bf16
    unsigned u = __float_as_uint(v);
    return (u16)((u + 0x7fffu + ((u >> 16) & 1u)) >> 16);
}
__device__ inline float bflo(u32 v) { return __uint_as_float(v << 16); }
__device__ inline float bfhi(u32 v) { return __uint_as_float(v & 0xffff0000u); }
__device__ inline float bf2f(u16 v) { return __uint_as_float(((u32)v) << 16); }

// ---------- pass A: degree histograms + per-edge rank in dst bucket ----------
// cd padded: one counter per 64B line (stride 16) -> no line-level RMW contention
__global__ __launch_bounds__(TB) void k_counts(const int* __restrict__ src,
                                               const int* __restrict__ dst,
                                               int* __restrict__ cs,
                                               int* __restrict__ cdp,
                                               int* __restrict__ rank, int E) {
    int e = blockIdx.x * TB + threadIdx.x;
    if (e < E) {
        atomicAdd(&cs[src[e]], 1);
        rank[e] = atomicAdd(&cdp[(size_t)dst[e] * 16], 1);
    }
}

// ---------- CSR build ----------
// scan_a reads the padded histogram (stride 16)
__global__ __launch_bounds__(TB) void k_scan_a(const int* __restrict__ cdp,
                                               int* __restrict__ excl,
                                               int* __restrict__ bsum, int N) {
    __shared__ int s[TB];
    int t = threadIdx.x;
    int i = blockIdx.x * TB + t;
    int v = (i < N) ? cdp[(size_t)i * 16] : 0;
    s[t] = v;
    __syncthreads();
    for (int o = 1; o < TB; o <<= 1) {
        int add = (t >= o) ? s[t - o] : 0;
        __syncthreads();
        s[t] += add;
        __syncthreads();
    }
    if (i < N) excl[i] = s[t] - v;
    if (t == TB - 1) bsum[blockIdx.x] = s[t];
}

__global__ __launch_bounds__(1024) void k_scan_b(int* __restrict__ bsum, int nb) {
    __shared__ int s[1024];
    int t = threadIdx.x;
    int v = (t < nb) ? bsum[t] : 0;
    s[t] = v;
    __syncthreads();
    for (int o = 1; o < 1024; o <<= 1) {
        int add = (t >= o) ? s[t - o] : 0;
        __syncthreads();
        s[t] += add;
        __syncthreads();
    }
    if (t < nb) bsum[t] = s[t] - v;
}

__global__ __launch_bounds__(TB) void k_scan_c(int* __restrict__ rowptr,
                                               const int* __restrict__ bsum,
                                               const int* __restrict__ cs,
                                               float* __restrict__ dinv,
                                               int N, int E) {
    int i = blockIdx.x * TB + threadIdx.x;
    if (i < N) {
        rowptr[i] += bsum[blockIdx.x];
        int d = cs[i];
        dinv[i] = d > 0 ? rsqrtf((float)d) : 0.f;
    }
    if (i == 0) rowptr[N] = E;
}

__global__ __launch_bounds__(TB) void k_fill(const int* __restrict__ src,
                                             const int* __restrict__ dst,
                                             const int* __restrict__ rank,
                                             const int* __restrict__ rowptr,
                                             const float* __restrict__ dinv,
                                             int2* __restrict__ csr, int E) {
    int e = blockIdx.x * TB + threadIdx.x;
    if (e < E) {
        int s = src[e], d = dst[e];
        float w = -dinv[s] * dinv[d];
        int pos = rowptr[d] + rank[e];
        csr[pos] = make_int2(s, __float_as_int(w));
    }
}

// ---------- layer-1 (Fin=1) props: 16 lanes per node ----------
__global__ __launch_bounds__(TB) void k_gather1(const float* __restrict__ in,
                                                const float* __restrict__ prev,
                                                float* __restrict__ out,
                                                const int* __restrict__ rowptr,
                                                const int2* __restrict__ csr,
                                                float scale, float scale0, int N) {
    int l16 = threadIdx.x & 15;
    int n = blockIdx.x * (TB / 16) + (threadIdx.x >> 4);
    if (n >= N) return;
    int beg = rowptr[n], end = rowptr[n + 1];
    float s = 0.f;
    for (int i = beg + l16; i < end; i += 16) {
        int2 e = csr[i];
        s = fmaf(__int_as_float(e.y), in[e.x], s);
    }
    s += __shfl_down(s, 8, 16);
    s += __shfl_down(s, 4, 16);
    s += __shfl_down(s, 2, 16);
    s += __shfl_down(s, 1, 16);
    if (l16 == 0) out[n] = fmaf(scale, s, scale0 * prev[n]);
}

// Layer 1 combine: h = relu(b1 + sum_k t_k * W1[k]) -> bf16
__global__ __launch_bounds__(TB) void k_layer1(const float* __restrict__ x,
                                               const float* __restrict__ t1,
                                               const float* __restrict__ t2,
                                               const float* __restrict__ t3,
                                               const float* __restrict__ t4,
                                               const float* __restrict__ W1,
                                               const float* __restrict__ b1,
                                               u16* __restrict__ Hb, int N) {
    int tid = blockIdx.x * TB + threadIdx.x;
    if (tid >= N * 64) return;
    int n = tid >> 6, f = tid & 63;
    float v = b1[f];
    v = fmaf(x[n],  W1[f],       v);
    v = fmaf(t1[n], W1[64 + f],  v);
    v = fmaf(t2[n], W1[128 + f], v);
    v = fmaf(t3[n], W1[192 + f], v);
    v = fmaf(t4[n], W1[256 + f], v);
    Hb[tid] = f2bf(fmaxf(v, 0.f));
}

// ---------- prop: bf16 gather, 4-deep MLP (step-32, 4 slots/group) ----------
// group g = lane>>3; lane p = lane&7 covers feats 8p..8p+7 via one uint4.
// 4 clamped edge slots per group per iteration: invalid slots load csr[beg]'s
// row (L1-hit broadcast, w=0). Butterfly over groups; lanes 0-7 write uint4.
__global__ __launch_bounds__(TB) void k_gather64o(const u16* __restrict__ inb,
                                                  const u16* __restrict__ prevb,
                                                  u16* __restrict__ outB,
                                                  const int* __restrict__ rowptr,
                                                  const int2* __restrict__ csr,
                                                  float scale, float scale0, int N) {
    int lane = threadIdx.x & 63;
    int g = lane >> 3;
    int p = lane & 7;
    int n = blockIdx.x * (TB / 64) + (threadIdx.x >> 6);
    if (n >= N) return;
    int beg = rowptr[n], end = rowptr[n + 1];
    float s0 = 0.f, s1 = 0.f, s2 = 0.f, s3 = 0.f;
    float s4 = 0.f, s5 = 0.f, s6 = 0.f, s7 = 0.f;
    const u16* bp = inb + 8 * p;
    for (int i0 = beg; i0 < end; i0 += 32) {
        int ia = i0 + g, ib = ia + 8, ic = ia + 16, id = ia + 24;
        bool va = ia < end, vb = ib < end, vc = ic < end, vd = id < end;
        int2 ea = csr[va ? ia : beg];
        int2 eb = csr[vb ? ib : beg];
        int2 ec = csr[vc ? ic : beg];
        int2 ed = csr[vd ? id : beg];
        uint4 ra = *(const uint4*)(bp + (size_t)ea.x * 64);
        uint4 rb = *(const uint4*)(bp + (size_t)eb.x * 64);
        uint4 rc = *(const uint4*)(bp + (size_t)ec.x * 64);
        uint4 rd = *(const uint4*)(bp + (size_t)ed.x * 64);
        float wa = va ? __int_as_float(ea.y) : 0.f;
        float wb = vb ? __int_as_float(eb.y) : 0.f;
        float wc = vc ? __int_as_float(ec.y) : 0.f;
        float wd = vd ? __int_as_float(ed.y) : 0.f;
        s0 = fmaf(wa, bflo(ra.x), s0); s1 = fmaf(wa, bfhi(ra.x), s1);
        s2 = fmaf(wa, bflo(ra.y), s2); s3 = fmaf(wa, bfhi(ra.y), s3);
        s4 = fmaf(wa, bflo(ra.z), s4); s5 = fmaf(wa, bfhi(ra.z), s5);
        s6 = fmaf(wa, bflo(ra.w), s6); s7 = fmaf(wa, bfhi(ra.w), s7);
        s0 = fmaf(wb, bflo(rb.x), s0); s1 = fmaf(wb, bfhi(rb.x), s1);
        s2 = fmaf(wb, bflo(rb.y), s2); s3 = fmaf(wb, bfhi(rb.y), s3);
        s4 = fmaf(wb, bflo(rb.z), s4); s5 = fmaf(wb, bfhi(rb.z), s5);
        s6 = fmaf(wb, bflo(rb.w), s6); s7 = fmaf(wb, bfhi(rb.w), s7);
        s0 = fmaf(wc, bflo(rc.x), s0); s1 = fmaf(wc, bfhi(rc.x), s1);
        s2 = fmaf(wc, bflo(rc.y), s2); s3 = fmaf(wc, bfhi(rc.y), s3);
        s4 = fmaf(wc, bflo(rc.z), s4); s5 = fmaf(wc, bfhi(rc.z), s5);
        s6 = fmaf(wc, bflo(rc.w), s6); s7 = fmaf(wc, bfhi(rc.w), s7);
        s0 = fmaf(wd, bflo(rd.x), s0); s1 = fmaf(wd, bfhi(rd.x), s1);
        s2 = fmaf(wd, bflo(rd.y), s2); s3 = fmaf(wd, bfhi(rd.y), s3);
        s4 = fmaf(wd, bflo(rd.z), s4); s5 = fmaf(wd, bfhi(rd.z), s5);
        s6 = fmaf(wd, bflo(rd.w), s6); s7 = fmaf(wd, bfhi(rd.w), s7);
    }
#pragma unroll
    for (int o = 8; o < 64; o <<= 1) {
        s0 += __shfl_xor(s0, o, 64); s1 += __shfl_xor(s1, o, 64);
        s2 += __shfl_xor(s2, o, 64); s3 += __shfl_xor(s3, o, 64);
        s4 += __shfl_xor(s4, o, 64); s5 += __shfl_xor(s5, o, 64);
        s6 += __shfl_xor(s6, o, 64); s7 += __shfl_xor(s7, o, 64);
    }
    if (lane < 8) {
        size_t o = (size_t)n * 64 + 8 * p;
        float t0 = scale * s0, t1 = scale * s1, t2 = scale * s2, t3 = scale * s3;
        float t4 = scale * s4, t5 = scale * s5, t6 = scale * s6, t7 = scale * s7;
        if (scale0 != 0.f) {
            uint4 pv = *(const uint4*)(prevb + o);
            t0 = fmaf(scale0, bflo(pv.x), t0); t1 = fmaf(scale0, bfhi(pv.x), t1);
            t2 = fmaf(scale0, bflo(pv.y), t2); t3 = fmaf(scale0, bfhi(pv.y), t3);
            t4 = fmaf(scale0, bflo(pv.z), t4); t5 = fmaf(scale0, bfhi(pv.z), t5);
            t6 = fmaf(scale0, bflo(pv.w), t6); t7 = fmaf(scale0, bfhi(pv.w), t7);
        }
        uint4 b;
        b.x = ((u32)f2bf(t1) << 16) | (u32)f2bf(t0);
        b.y = ((u32)f2bf(t3) << 16) | (u32)f2bf(t2);
        b.z = ((u32)f2bf(t5) << 16) | (u32)f2bf(t4);
        b.w = ((u32)f2bf(t7) << 16) | (u32)f2bf(t6);
        *(uint4*)(outB + o) = b;
    }
}

// ---------- paired dense (bf16 inputs): acc (=|+=) [b +] QA@Wa + QB@Wb ----------
__global__ __launch_bounds__(TB) void k_matmul2(const u16* __restrict__ QA,
                                                const u16* __restrict__ QB,
                                                const float* __restrict__ Wa,
                                                const float* __restrict__ Wb,
                                                const float* __restrict__ bias,
                                                float* __restrict__ acc,
                                                int initFlag, int N) {
    int lane = threadIdx.x & 63;
    int wid = blockIdx.x * (TB / 64) + (threadIdx.x >> 6);
    int nw = gridDim.x * (TB / 64);

    float wa[64], wb[64];
#pragma unroll
    for (int j = 0; j < 64; ++j) wa[j] = Wa[j * 64 + lane];
#pragma unroll
    for (int j = 0; j < 64; ++j) wb[j] = Wb[j * 64 + lane];
    float bv = bias[lane];

    for (int n = wid; n < N; n += nw) {
        size_t o = (size_t)n * 64;
        float a = initFlag ? bv : acc[o + lane];
        const uint4* ra = (const uint4*)(QA + o);
        const uint4* rb = (const uint4*)(QB + o);
#pragma unroll
        for (int j8 = 0; j8 < 8; ++j8) {
            uint4 r = ra[j8];
            a = fmaf(bflo(r.x), wa[8 * j8 + 0], a);
            a = fmaf(bfhi(r.x), wa[8 * j8 + 1], a);
            a = fmaf(bflo(r.y), wa[8 * j8 + 2], a);
            a = fmaf(bfhi(r.y), wa[8 * j8 + 3], a);
            a = fmaf(bflo(r.z), wa[8 * j8 + 4], a);
            a = fmaf(bfhi(r.z), wa[8 * j8 + 5], a);
            a = fmaf(bflo(r.w), wa[8 * j8 + 6], a);
            a = fmaf(bfhi(r.w), wa[8 * j8 + 7], a);
        }
#pragma unroll
        for (int j8 = 0; j8 < 8; ++j8) {
            uint4 r = rb[j8];
            a = fmaf(bflo(r.x), wb[8 * j8 + 0], a);
            a = fmaf(bfhi(r.x), wb[8 * j8 + 1], a);
            a = fmaf(bflo(r.y), wb[8 * j8 + 2], a);
            a = fmaf(bfhi(r.y), wb[8 * j8 + 3], a);
            a = fmaf(bflo(r.z), wb[8 * j8 + 4], a);
            a = fmaf(bfhi(r.z), wb[8 * j8 + 5], a);
            a = fmaf(bflo(r.w), wb[8 * j8 + 6], a);
            a = fmaf(bfhi(r.w), wb[8 * j8 + 7], a);
        }
        acc[o + lane] = a;
    }
}

// ---------- final dense of a layer: h = relu(acc + bf(Qx)@W) -> bf16 ----------
__global__ __launch_bounds__(TB) void k_matmulR(const u16* __restrict__ Qx,
                                                const float* __restrict__ W,
                                                const float* __restrict__ acc,
                                                u16* __restrict__ hB, int N) {
    int lane = threadIdx.x & 63;
    int wid = blockIdx.x * (TB / 64) + (threadIdx.x >> 6);
    int nw = gridDim.x * (TB / 64);

    float wcol[64];
#pragma unroll
    for (int j = 0; j < 64; ++j) wcol[j] = W[j * 64 + lane];

    for (int n = wid; n < N; n += nw) {
        size_t o = (size_t)n * 64;
        float a = acc[o + lane];
        const uint4* row = (const uint4*)(Qx + o);
#pragma unroll
        for (int j8 = 0; j8 < 8; ++j8) {
            uint4 r = row[j8];
            a = fmaf(bflo(r.x), wcol[8 * j8 + 0], a);
            a = fmaf(bfhi(r.x), wcol[8 * j8 + 1], a);
            a = fmaf(bflo(r.y), wcol[8 * j8 + 2], a);
            a = fmaf(bfhi(r.y), wcol[8 * j8 + 3], a);
            a = fmaf(bflo(r.z), wcol[8 * j8 + 4], a);
            a = fmaf(bfhi(r.z), wcol[8 * j8 + 5], a);
            a = fmaf(bflo(r.w), wcol[8 * j8 + 6], a);
            a = fmaf(bfhi(r.w), wcol[8 * j8 + 7], a);
        }
        hB[o + lane] = f2bf(fmaxf(a, 0.f));
    }
}

// ---------- final head: out = bfc + h @ Wfc (h bf16) ----------
__global__ __launch_bounds__(TB) void k_final(const u16* __restrict__ A,
                                              const float* __restrict__ Wfc,
                                              const float* __restrict__ bfc,
                                              float* __restrict__ out, int N) {
    int lane = threadIdx.x & 63;
    int wid = blockIdx.x * (TB / 64) + (threadIdx.x >> 6);
    if (wid >= N) return;
    float v = bf2f(A[(size_t)wid * 64 + lane]) * Wfc[lane];
#pragma unroll
    for (int o = 32; o > 0; o >>= 1) v += __shfl_down(v, o, 64);
    if (lane == 0) out[wid] = v + bfc[0];
}

extern "C" void kernel_launch(void* const* d_in, const int* in_sizes, int n_in,
                              void* d_out, int out_size, void* d_ws, size_t ws_size,
                              hipStream_t stream) {
    const float* x   = (const float*)d_in[0];
    const int*   ei  = (const int*)d_in[1];
    const float* W1  = (const float*)d_in[2];
    const float* b1  = (const float*)d_in[3];
    const float* W2  = (const float*)d_in[4];
    const float* b2  = (const float*)d_in[5];
    const float* W3  = (const float*)d_in[6];
    const float* b3  = (const float*)d_in[7];
    const float* Wfc = (const float*)d_in[8];
    const float* bfc = (const float*)d_in[9];
    float* out = (float*)d_out;

    const int N = in_sizes[0];
    const int E = in_sizes[1] / 2;
    const int* src = ei;
    const int* dst = ei + E;
    const size_t NF = (size_t)N * 64;

    // workspace layout
    char* p = (char*)d_ws;
    float* ACC = (float*)p; p += NF * 4;
    u16* QA = (u16*)p; p += NF * 2;           // bf16 activation rotation (4 bufs)
    u16* QB = (u16*)p; p += NF * 2;
    u16* QC = (u16*)p; p += NF * 2;
    u16* QD = (u16*)p; p += NF * 2;
    int2* csr = (int2*)p; p += (size_t)E * 8;
    int* rank = (int*)p; p += (size_t)E * 4;
    int* cdp  = (int*)p; p += (size_t)N * 16 * 4;   // padded dst histogram
    float* t1 = (float*)p; p += (size_t)N * 4;
    float* t2 = (float*)p; p += (size_t)N * 4;
    float* t3 = (float*)p; p += (size_t)N * 4;
    float* t4 = (float*)p; p += (size_t)N * 4;
    float* dinv = (float*)p; p += (size_t)N * 4;
    int* cs     = (int*)p; p += (size_t)N * 4;
    int* rowptr = (int*)p; p += (size_t)(N + 1) * 4;
    int* bsum   = (int*)p; p += 1024 * 4;

    const int gE   = (E + TB - 1) / TB;
    const int gN   = (N + TB - 1) / TB;                // scan blocks (<=1024)
    const int gN16 = (N * 16 + TB - 1) / TB;           // 16 lanes/node
    const int gNW  = (N + 3) / 4;                      // wave-per-node
    const int gNF  = (int)((NF + TB - 1) / TB);
    const int gMM  = 3200;                             // dense grid-stride

    // norm + CSR build
    hipMemsetAsync(cs, 0, (size_t)N * 4, stream);
    hipMemsetAsync(cdp, 0, (size_t)N * 16 * 4, stream);
    k_counts<<<gE, TB, 0, stream>>>(src, dst, cs, cdp, rank, E);
    k_scan_a<<<gN, TB, 0, stream>>>(cdp, rowptr, bsum, N);
    k_scan_b<<<1, 1024, 0, stream>>>(bsum, gN);
    k_scan_c<<<gN, TB, 0, stream>>>(rowptr, bsum, cs, dinv, N, E);
    k_fill<<<gE, TB, 0, stream>>>(src, dst, rank, rowptr, dinv, csr, E);

    // --- Layer 1 (Fin=1) ---
    k_gather1<<<gN16, TB, 0, stream>>>(x,  x,  t1, rowptr, csr, 1.f,  0.f, N);
    k_gather1<<<gN16, TB, 0, stream>>>(t1, x,  t2, rowptr, csr, 2.f, -1.f, N);
    k_gather1<<<gN16, TB, 0, stream>>>(t2, t1, t3, rowptr, csr, 2.f, -1.f, N);
    k_gather1<<<gN16, TB, 0, stream>>>(t3, t2, t4, rowptr, csr, 2.f, -1.f, N);
    k_layer1<<<gNF, TB, 0, stream>>>(x, t1, t2, t3, t4, W1, b1, QA, N);

    // --- Layers 2 & 3 (Fin=64), all-bf16 activations ---
    // h=A. gT1: A->B. mm01(A,B). gT2: in=B prev=A -> C. gT3: in=C prev=B -> D.
    // mm23(C,D). gT4: in=D prev=C -> A. mmR(A) -> h'=B. Next: h=B.
    u16 *A = QA, *B = QB, *C = QC, *D = QD;
    for (int layer = 0; layer < 2; ++layer) {
        const float* W = (layer == 0) ? W2 : W3;
        const float* b = (layer == 0) ? b2 : b3;
        k_gather64o<<<gNW, TB, 0, stream>>>(A, A, B, rowptr, csr, 1.f,  0.f, N);
        k_matmul2<<<gMM, TB, 0, stream>>>(A, B, W + 0 * 4096, W + 1 * 4096, b, ACC, 1, N);
        k_gather64o<<<gNW, TB, 0, stream>>>(B, A, C, rowptr, csr, 2.f, -1.f, N);
        k_gather64o<<<gNW, TB, 0, stream>>>(C, B, D, rowptr, csr, 2.f, -1.f, N);
        k_matmul2<<<gMM, TB, 0, stream>>>(C, D, W + 2 * 4096, W + 3 * 4096, b, ACC, 0, N);
        k_gather64o<<<gNW, TB, 0, stream>>>(D, C, A, rowptr, csr, 2.f, -1.f, N);
        k_matmulR<<<gMM, TB, 0, stream>>>(A, W + 4 * 4096, ACC, B, N);
        // rotate: new h = B; reuse old A,C,D as scratch
        u16* nh = B; B = C; C = D; D = A; A = nh;
    }

    // --- Final head: h = A (bf16) ---
    k_final<<<gNW, TB, 0, stream>>>(A, Wfc, bfc, out, N);
}